// Round 2
// baseline (365.381 us; speedup 1.0000x reference)
//
#include <hip/hip_runtime.h>

#define BB 2
#define CC 128
#define HH 64
#define WW 64
#define HEADS 4
#define DHEAD 32
#define KW 7
#define GROUPS 32
#define HW 4096
#define EPS 1e-5f

// workspace layout (float offsets)
#define OFF_STATS 0
#define OFF_WC    128
#define OFF_BC    (OFF_WC + 384*128)
#define OFF_Q     (OFF_BC + 384)
#define OFF_K     (OFF_Q + 8*4096*32)
#define OFF_V     (OFF_K + 8*4096*32)

// K0: concat wq/wk/wv into Wc[384][128], fold q-scale into rows 0..127; same for bias
__global__ void k0_prep(const float* __restrict__ wq, const float* __restrict__ bq,
                        const float* __restrict__ wk, const float* __restrict__ bk,
                        const float* __restrict__ wv, const float* __restrict__ bv,
                        float* __restrict__ Wc, float* __restrict__ bc) {
  int t = blockIdx.x * 256 + threadIdx.x;
  const float qs = 0.17677669529663687f;  // 1/sqrt(32)
  if (t < 128 * 128) {
    Wc[t]           = wq[t] * qs;
    Wc[16384 + t]   = wk[t];
    Wc[32768 + t]   = wv[t];
  }
  if (t < 128) {
    bc[t]       = bq[t] * qs;
    bc[128 + t] = bk[t];
    bc[256 + t] = bv[t];
  }
}

// K1: GroupNorm stats: one block per (b, group); group = 4 channels x 4096 = 16384 floats
__global__ __launch_bounds__(256) void k1_stats(const float* __restrict__ x,
                                                float* __restrict__ stats) {
  int g = blockIdx.x;  // 0..63 = b*32 + grp
  const float4* xp = (const float4*)(x + (size_t)g * 16384);
  float s = 0.f, s2 = 0.f;
  for (int i = threadIdx.x; i < 4096; i += 256) {
    float4 v = xp[i];
    s  += v.x + v.y + v.z + v.w;
    s2 += v.x*v.x + v.y*v.y + v.z*v.z + v.w*v.w;
  }
  #pragma unroll
  for (int o = 32; o; o >>= 1) {
    s  += __shfl_down(s, o, 64);
    s2 += __shfl_down(s2, o, 64);
  }
  __shared__ float ls[4], ls2[4];
  int wid = threadIdx.x >> 6, lane = threadIdx.x & 63;
  if (!lane) { ls[wid] = s; ls2[wid] = s2; }
  __syncthreads();
  if (threadIdx.x == 0) {
    float S = 0.f, S2 = 0.f;
    #pragma unroll
    for (int i = 0; i < 4; i++) { S += ls[i]; S2 += ls2[i]; }
    float mean = S * (1.f / 16384.f);
    float var  = S2 * (1.f / 16384.f) - mean * mean;
    stats[g]      = mean;
    stats[64 + g] = rsqrtf(var + EPS);
  }
}

// K2: fused GN-normalize + QKV projection. tile = 64 pixels, 4 waves, wave g owns 96 outputs.
__global__ __launch_bounds__(256) void k2_qkv(
    const float* __restrict__ x, const float* __restrict__ stats,
    const float* __restrict__ gw, const float* __restrict__ gb,
    const float* __restrict__ Wc, const float* __restrict__ bc,
    float* __restrict__ qkv) {
  __shared__ float xn[128][64];   // 32 KB, [c][pixel]
  int tile  = blockIdx.x;          // 0..127
  int b     = tile >> 6;           // 64 tiles per batch image
  int pbase = (tile & 63) * 64;    // within-batch pixel base
  for (int e = threadIdx.x; e < 8192; e += 256) {
    int c = e >> 6, pl = e & 63;
    float v = x[((size_t)b * CC + c) * HW + pbase + pl];
    int grp = b * 32 + (c >> 2);
    xn[c][pl] = (v - stats[grp]) * stats[64 + grp] * gw[c] + gb[c];
  }
  __syncthreads();
  int g  = __builtin_amdgcn_readfirstlane(threadIdx.x >> 6);
  int p  = threadIdx.x & 63;
  int og = g * 96;
  float acc[96];
  #pragma unroll
  for (int j = 0; j < 96; j++) acc[j] = bc[og + j];
  const float4* W4 = (const float4*)Wc;
  for (int c4 = 0; c4 < 32; ++c4) {
    float xc0 = xn[c4*4+0][p];
    float xc1 = xn[c4*4+1][p];
    float xc2 = xn[c4*4+2][p];
    float xc3 = xn[c4*4+3][p];
    #pragma unroll
    for (int j = 0; j < 96; j++) {
      float4 w = W4[(og + j) * 32 + c4];
      acc[j] = fmaf(xc0, w.x, fmaf(xc1, w.y, fmaf(xc2, w.z, fmaf(xc3, w.w, acc[j]))));
    }
  }
  int ploc = pbase + p;  // within-batch pixel
  #pragma unroll
  for (int j = 0; j < 96; j += 4) {
    int o = og + j;
    int mat = o >> 7, r = o & 127;
    int head = r >> 5, d = r & 31;
    float4 st = make_float4(acc[j], acc[j+1], acc[j+2], acc[j+3]);
    *(float4*)&qkv[(size_t)mat * (8*4096*32) + (((size_t)b*4 + head) * 4096 + ploc) * 32 + d] = st;
  }
}

// K3: neighborhood attention, one thread per (b, head, pixel).
// NOTE the reference's out.reshape(B,H,W,128) mixes head into spatial dims:
//   flat f = head*131072 + h*2048 + w*32 + d  ->  (h', w', c') with
//   c' = (w%4)*32 + d ; h' = head*16 + h/4 ; w' = (h%4)*16 + w/4
// so xo[b, c', h', w'] (bijective). We scatter-write that layout directly.
__global__ __launch_bounds__(256) void k3_attn(
    const float* __restrict__ q, const float* __restrict__ k, const float* __restrict__ v,
    const float* __restrict__ rpb, float* __restrict__ xo) {
  int t   = blockIdx.x * 256 + threadIdx.x;  // 0..32767
  int bh  = t >> 12;
  int pix = t & 4095;
  int y   = pix >> 6, xq = pix & 63;
  int head = bh & 3, b = bh >> 2;
  const float* qp = q + ((size_t)bh * 4096 + pix) * 32;
  float qr[32];
  #pragma unroll
  for (int d4 = 0; d4 < 8; d4++) {
    float4 v4 = *(const float4*)(qp + d4 * 4);
    qr[d4*4] = v4.x; qr[d4*4+1] = v4.y; qr[d4*4+2] = v4.z; qr[d4*4+3] = v4.w;
  }
  int ys  = min(max(y  - 3, 0), 57);
  int xs  = min(max(xq - 3, 0), 57);
  int pbh = 3 + max(3 - y, 0)  + min(60 - y, 0);
  int pbw = 3 + max(3 - xq, 0) + min(60 - xq, 0);
  const float* rp = rpb + head * 169;
  float logits[49];
  #pragma unroll
  for (int dy = 0; dy < 7; dy++) {
    #pragma unroll
    for (int dx = 0; dx < 7; dx++) {
      const float* kp = k + ((size_t)bh * 4096 + (ys + dy) * 64 + xs + dx) * 32;
      float acc = 0.f;
      #pragma unroll
      for (int d4 = 0; d4 < 8; d4++) {
        float4 kv = *(const float4*)(kp + d4 * 4);
        acc = fmaf(qr[d4*4], kv.x, fmaf(qr[d4*4+1], kv.y,
              fmaf(qr[d4*4+2], kv.z, fmaf(qr[d4*4+3], kv.w, acc))));
      }
      logits[dy*7+dx] = acc + rp[(pbh + dy) * 13 + pbw + dx];
    }
  }
  float m = logits[0];
  #pragma unroll
  for (int i = 1; i < 49; i++) m = fmaxf(m, logits[i]);
  float s = 0.f;
  #pragma unroll
  for (int i = 0; i < 49; i++) { logits[i] = __expf(logits[i] - m); s += logits[i]; }
  float inv = 1.f / s;
  float out[32];
  #pragma unroll
  for (int d = 0; d < 32; d++) out[d] = 0.f;
  #pragma unroll
  for (int dy = 0; dy < 7; dy++) {
    #pragma unroll
    for (int dx = 0; dx < 7; dx++) {
      const float* vp = v + ((size_t)bh * 4096 + (ys + dy) * 64 + xs + dx) * 32;
      float pw = logits[dy*7+dx];
      #pragma unroll
      for (int d4 = 0; d4 < 8; d4++) {
        float4 vv = *(const float4*)(vp + d4 * 4);
        out[d4*4]   = fmaf(pw, vv.x, out[d4*4]);
        out[d4*4+1] = fmaf(pw, vv.y, out[d4*4+1]);
        out[d4*4+2] = fmaf(pw, vv.z, out[d4*4+2]);
        out[d4*4+3] = fmaf(pw, vv.w, out[d4*4+3]);
      }
    }
  }
  // scrambled-reshape write
  int cbase = (xq & 3) * 32;
  int hp    = head * 16 + (y >> 2);
  int wp    = ((y & 3) << 4) + (xq >> 2);
  int sp    = hp * 64 + wp;
  #pragma unroll
  for (int d = 0; d < 32; d++)
    xo[((size_t)b * 128 + cbase + d) * 4096 + sp] = out[d] * inv;
}

// K4: output projection, same structure as K2 (wave g owns 32 output channels).
// xo aliases d_out: each block reads only its own 64 pixels (staged to LDS,
// __syncthreads) before overwriting them; no cross-block overlap.
__global__ __launch_bounds__(256) void k4_proj(
    const float* __restrict__ xo, const float* __restrict__ wo, const float* __restrict__ bo,
    float* __restrict__ out) {
  __shared__ float xs[128][64];
  int tile  = blockIdx.x;
  int b     = tile >> 6;
  int pbase = (tile & 63) * 64;
  for (int e = threadIdx.x; e < 8192; e += 256) {
    int c = e >> 6, pl = e & 63;
    xs[c][pl] = xo[((size_t)b * 128 + c) * 4096 + pbase + pl];
  }
  __syncthreads();
  int g  = __builtin_amdgcn_readfirstlane(threadIdx.x >> 6);
  int p  = threadIdx.x & 63;
  int og = g * 32;
  float acc[32];
  #pragma unroll
  for (int j = 0; j < 32; j++) acc[j] = bo[og + j];
  const float4* W4 = (const float4*)wo;
  for (int c4 = 0; c4 < 32; ++c4) {
    float x0 = xs[c4*4+0][p];
    float x1 = xs[c4*4+1][p];
    float x2 = xs[c4*4+2][p];
    float x3 = xs[c4*4+3][p];
    #pragma unroll
    for (int j = 0; j < 32; j++) {
      float4 w = W4[(og + j) * 32 + c4];
      acc[j] = fmaf(x0, w.x, fmaf(x1, w.y, fmaf(x2, w.z, fmaf(x3, w.w, acc[j]))));
    }
  }
  #pragma unroll
  for (int j = 0; j < 32; j++)
    out[((size_t)b * 128 + og + j) * 4096 + pbase + p] = acc[j];
}

extern "C" void kernel_launch(void* const* d_in, const int* in_sizes, int n_in,
                              void* d_out, int out_size, void* d_ws, size_t ws_size,
                              hipStream_t stream) {
  (void)in_sizes; (void)n_in; (void)out_size; (void)ws_size;
  const float* x   = (const float*)d_in[0];
  const float* gw  = (const float*)d_in[1];
  const float* gb  = (const float*)d_in[2];
  const float* wq  = (const float*)d_in[3];
  const float* bq  = (const float*)d_in[4];
  const float* wk  = (const float*)d_in[5];
  const float* bk  = (const float*)d_in[6];
  const float* wv  = (const float*)d_in[7];
  const float* bv  = (const float*)d_in[8];
  const float* wo  = (const float*)d_in[9];
  const float* bo  = (const float*)d_in[10];
  const float* rpb = (const float*)d_in[11];
  float* ws    = (float*)d_ws;
  float* stats = ws + OFF_STATS;
  float* Wc    = ws + OFF_WC;
  float* bc    = ws + OFF_BC;
  float* q     = ws + OFF_Q;
  float* kk    = ws + OFF_K;
  float* v     = ws + OFF_V;
  float* out   = (float*)d_out;
  float* xo    = out;  // aliased (see k4 comment)

  hipLaunchKernelGGL(k0_prep,  dim3(64),  dim3(256), 0, stream, wq, bq, wk, bk, wv, bv, Wc, bc);
  hipLaunchKernelGGL(k1_stats, dim3(64),  dim3(256), 0, stream, x, stats);
  hipLaunchKernelGGL(k2_qkv,   dim3(128), dim3(256), 0, stream, x, stats, gw, gb, Wc, bc, q);
  hipLaunchKernelGGL(k3_attn,  dim3(128), dim3(256), 0, stream, q, kk, v, rpb, xo);
  hipLaunchKernelGGL(k4_proj,  dim3(128), dim3(256), 0, stream, xo, wo, bo, out);
}

// Round 3
// 131.941 us; speedup vs baseline: 2.7693x; 2.7693x over previous
//
#include <hip/hip_runtime.h>

#define EPS 1e-5f

typedef short s8v __attribute__((ext_vector_type(8)));   // 8 bf16 in 4 VGPRs
typedef float f4v __attribute__((ext_vector_type(4)));

static __device__ inline short f2bf(float f) {
  return __builtin_bit_cast(short, (__bf16)f);
}

// workspace layout (float offsets)
#define OFF_STATS 0
#define OFF_WCB   128                     // bf16[384*128] = 24576 float slots
#define OFF_BC    (OFF_WCB + 24576)
#define OFF_Q     (OFF_BC + 384)
#define OFF_K     (OFF_Q + 1048576)
#define OFF_V     (OFF_K + 1048576)

// K0: concat wq/wk/wv -> bf16 Wcb[384][128], fold q-scale into rows 0..127; bias stays fp32
__global__ void k0_prep(const float* __restrict__ wq, const float* __restrict__ bq,
                        const float* __restrict__ wk, const float* __restrict__ bk,
                        const float* __restrict__ wv, const float* __restrict__ bv,
                        short* __restrict__ Wcb, float* __restrict__ bc) {
  int t = blockIdx.x * 256 + threadIdx.x;   // 0..16383
  const float qs = 0.17677669529663687f;    // 1/sqrt(32)
  Wcb[t]         = f2bf(wq[t] * qs);
  Wcb[16384 + t] = f2bf(wk[t]);
  Wcb[32768 + t] = f2bf(wv[t]);
  if (t < 128) {
    bc[t]       = bq[t] * qs;
    bc[128 + t] = bk[t];
    bc[256 + t] = bv[t];
  }
}

// K1: GroupNorm stats, one block per (b, group)
__global__ __launch_bounds__(256) void k1_stats(const float* __restrict__ x,
                                                float* __restrict__ stats) {
  int g = blockIdx.x;  // 0..63
  const float4* xp = (const float4*)(x + (size_t)g * 16384);
  float s = 0.f, s2 = 0.f;
  for (int i = threadIdx.x; i < 4096; i += 256) {
    float4 v = xp[i];
    s  += v.x + v.y + v.z + v.w;
    s2 += v.x*v.x + v.y*v.y + v.z*v.z + v.w*v.w;
  }
  #pragma unroll
  for (int o = 32; o; o >>= 1) {
    s  += __shfl_down(s, o, 64);
    s2 += __shfl_down(s2, o, 64);
  }
  __shared__ float ls[4], ls2[4];
  int wid = threadIdx.x >> 6, lane = threadIdx.x & 63;
  if (!lane) { ls[wid] = s; ls2[wid] = s2; }
  __syncthreads();
  if (threadIdx.x == 0) {
    float S = 0.f, S2 = 0.f;
    #pragma unroll
    for (int i = 0; i < 4; i++) { S += ls[i]; S2 += ls2[i]; }
    float mean = S * (1.f / 16384.f);
    float var  = S2 * (1.f / 16384.f) - mean * mean;
    stats[g]      = mean;
    stats[64 + g] = rsqrtf(var + EPS);
  }
}

// K2: fused GN-normalize + QKV projection via MFMA.
// grid = 512: (pixel-tile 0..127) x (n-slice 0..3 of 96 outputs).
// wave w: M-tile = 16 pixels, 6 N-tiles of 16 -> acc 6x f4v (24 VGPR).
__global__ __launch_bounds__(256) void k2_qkv(
    const float* __restrict__ x, const float* __restrict__ stats,
    const float* __restrict__ gw, const float* __restrict__ gb,
    const short* __restrict__ Wcb, const float* __restrict__ bc,
    float* __restrict__ qkv) {
  __shared__ short xn[64][136];   // [pixel][channel], +8 pad -> 2-way-free b128 reads
  __shared__ short WL[96][136];
  int bid   = blockIdx.x;
  int ptile = bid >> 2, nslice = bid & 3;
  int b     = ptile >> 6;
  int pbase = (ptile & 63) * 64;
  int nbase = nslice * 96;
  int tid   = threadIdx.x;

  // stage GN-normalized x tile (pair of channels per iter -> 4B LDS writes)
  #pragma unroll
  for (int i = 0; i < 16; i++) {
    int e = tid + i * 256;          // 0..4095
    int c2 = e >> 6, px = e & 63;
    int c0 = c2 * 2;
    int grp = b * 32 + (c0 >> 2);
    float mu = stats[grp], rs = stats[64 + grp];
    float v0 = x[((size_t)(b * 128 + c0))     * 4096 + pbase + px];
    float v1 = x[((size_t)(b * 128 + c0 + 1)) * 4096 + pbase + px];
    v0 = (v0 - mu) * rs * gw[c0]     + gb[c0];
    v1 = (v1 - mu) * rs * gw[c0 + 1] + gb[c0 + 1];
    xn[px][c0]     = f2bf(v0);
    xn[px][c0 + 1] = f2bf(v1);
  }
  // stage weight slice (16B chunks)
  #pragma unroll
  for (int i = 0; i < 6; i++) {
    int cc = tid + i * 256;         // 0..1535
    int row = cc >> 4, c8 = (cc & 15) * 8;
    *(s8v*)&WL[row][c8] = *(const s8v*)&Wcb[(nbase + row) * 128 + c8];
  }
  __syncthreads();

  int w    = __builtin_amdgcn_readfirstlane(tid >> 6);
  int lane = tid & 63;
  int l15  = lane & 15, kh = lane >> 4;
  f4v acc[6];
  #pragma unroll
  for (int nt = 0; nt < 6; nt++) acc[nt] = (f4v){0.f, 0.f, 0.f, 0.f};
  #pragma unroll
  for (int ks = 0; ks < 4; ks++) {
    s8v a = *(s8v*)&xn[w * 16 + l15][ks * 32 + kh * 8];
    #pragma unroll
    for (int nt = 0; nt < 6; nt++) {
      s8v bb = *(s8v*)&WL[nt * 16 + l15][ks * 32 + kh * 8];
      acc[nt] = __builtin_amdgcn_mfma_f32_16x16x32_bf16(a, bb, acc[nt], 0, 0, 0);
    }
  }
  // epilogue: bias in fp32, scatter to q/k/v [mat][b*4+head][pix][d]
  #pragma unroll
  for (int nt = 0; nt < 6; nt++) {
    int o    = nbase + nt * 16 + l15;
    int mat  = o >> 7, rr = o & 127;
    int head = rr >> 5, d = rr & 31;
    float bias = bc[o];
    float* dst = qkv + (size_t)mat * 1048576 + ((size_t)(b * 4 + head) * 4096) * 32 + d;
    #pragma unroll
    for (int r = 0; r < 4; r++) {
      int px = pbase + w * 16 + kh * 4 + r;
      dst[(size_t)px * 32] = acc[nt][r] + bias;
    }
  }
}

// K3: neighborhood attention, one thread per (b, head, pixel). Unchanged (fp32).
// Writes xo in the reference's scrambled reshape layout:
//   c' = (w%4)*32 + d ; h' = head*16 + h/4 ; w' = (h%4)*16 + w/4
__global__ __launch_bounds__(256) void k3_attn(
    const float* __restrict__ q, const float* __restrict__ k, const float* __restrict__ v,
    const float* __restrict__ rpb, float* __restrict__ xo) {
  int t   = blockIdx.x * 256 + threadIdx.x;  // 0..32767
  int bh  = t >> 12;
  int pix = t & 4095;
  int y   = pix >> 6, xq = pix & 63;
  int head = bh & 3, b = bh >> 2;
  const float* qp = q + ((size_t)bh * 4096 + pix) * 32;
  float qr[32];
  #pragma unroll
  for (int d4 = 0; d4 < 8; d4++) {
    float4 v4 = *(const float4*)(qp + d4 * 4);
    qr[d4*4] = v4.x; qr[d4*4+1] = v4.y; qr[d4*4+2] = v4.z; qr[d4*4+3] = v4.w;
  }
  int ys  = min(max(y  - 3, 0), 57);
  int xs  = min(max(xq - 3, 0), 57);
  int pbh = 3 + max(3 - y, 0)  + min(60 - y, 0);
  int pbw = 3 + max(3 - xq, 0) + min(60 - xq, 0);
  const float* rp = rpb + head * 169;
  float logits[49];
  #pragma unroll
  for (int dy = 0; dy < 7; dy++) {
    #pragma unroll
    for (int dx = 0; dx < 7; dx++) {
      const float* kp = k + ((size_t)bh * 4096 + (ys + dy) * 64 + xs + dx) * 32;
      float acc = 0.f;
      #pragma unroll
      for (int d4 = 0; d4 < 8; d4++) {
        float4 kv = *(const float4*)(kp + d4 * 4);
        acc = fmaf(qr[d4*4], kv.x, fmaf(qr[d4*4+1], kv.y,
              fmaf(qr[d4*4+2], kv.z, fmaf(qr[d4*4+3], kv.w, acc))));
      }
      logits[dy*7+dx] = acc + rp[(pbh + dy) * 13 + pbw + dx];
    }
  }
  float m = logits[0];
  #pragma unroll
  for (int i = 1; i < 49; i++) m = fmaxf(m, logits[i]);
  float s = 0.f;
  #pragma unroll
  for (int i = 0; i < 49; i++) { logits[i] = __expf(logits[i] - m); s += logits[i]; }
  float inv = 1.f / s;
  float out[32];
  #pragma unroll
  for (int d = 0; d < 32; d++) out[d] = 0.f;
  #pragma unroll
  for (int dy = 0; dy < 7; dy++) {
    #pragma unroll
    for (int dx = 0; dx < 7; dx++) {
      const float* vp = v + ((size_t)bh * 4096 + (ys + dy) * 64 + xs + dx) * 32;
      float pw = logits[dy*7+dx];
      #pragma unroll
      for (int d4 = 0; d4 < 8; d4++) {
        float4 vv = *(const float4*)(vp + d4 * 4);
        out[d4*4]   = fmaf(pw, vv.x, out[d4*4]);
        out[d4*4+1] = fmaf(pw, vv.y, out[d4*4+1]);
        out[d4*4+2] = fmaf(pw, vv.z, out[d4*4+2]);
        out[d4*4+3] = fmaf(pw, vv.w, out[d4*4+3]);
      }
    }
  }
  int cbase = (xq & 3) * 32;
  int hp    = head * 16 + (y >> 2);
  int wp    = ((y & 3) << 4) + (xq >> 2);
  int sp    = hp * 64 + wp;
  #pragma unroll
  for (int d = 0; d < 32; d++)
    xo[((size_t)b * 128 + cbase + d) * 4096 + sp] = out[d] * inv;
}

// K4: output projection via MFMA. grid = 128 pixel-tiles.
// wave w: M-tile = 16 pixels, 8 N-tiles of 16 -> acc 8x f4v (32 VGPR).
// xo aliases d_out: block reads its own 64 pixels into LDS, syncs, overwrites.
__global__ __launch_bounds__(256) void k4_proj(
    const float* __restrict__ xo, const float* __restrict__ wo, const float* __restrict__ bo,
    float* __restrict__ out) {
  __shared__ short xs[64][136];
  __shared__ short WoL[128][136];
  int tile  = blockIdx.x;
  int b     = tile >> 6;
  int pbase = (tile & 63) * 64;
  int tid   = threadIdx.x;

  #pragma unroll
  for (int i = 0; i < 16; i++) {
    int e = tid + i * 256;
    int c2 = e >> 6, px = e & 63;
    int c0 = c2 * 2;
    xs[px][c0]     = f2bf(xo[((size_t)(b * 128 + c0))     * 4096 + pbase + px]);
    xs[px][c0 + 1] = f2bf(xo[((size_t)(b * 128 + c0 + 1)) * 4096 + pbase + px]);
  }
  #pragma unroll
  for (int i = 0; i < 8; i++) {
    int cc = tid + i * 256;        // 0..2047
    int row = cc >> 4, c8 = (cc & 15) * 8;
    const float* src = wo + row * 128 + c8;
    float4 f0 = *(const float4*)src, f1 = *(const float4*)(src + 4);
    s8v wv8;
    wv8[0] = f2bf(f0.x); wv8[1] = f2bf(f0.y); wv8[2] = f2bf(f0.z); wv8[3] = f2bf(f0.w);
    wv8[4] = f2bf(f1.x); wv8[5] = f2bf(f1.y); wv8[6] = f2bf(f1.z); wv8[7] = f2bf(f1.w);
    *(s8v*)&WoL[row][c8] = wv8;
  }
  __syncthreads();

  int w    = __builtin_amdgcn_readfirstlane(tid >> 6);
  int lane = tid & 63;
  int l15  = lane & 15, kh = lane >> 4;
  f4v acc[8];
  #pragma unroll
  for (int nt = 0; nt < 8; nt++) acc[nt] = (f4v){0.f, 0.f, 0.f, 0.f};
  #pragma unroll
  for (int ks = 0; ks < 4; ks++) {
    s8v a = *(s8v*)&xs[w * 16 + l15][ks * 32 + kh * 8];
    #pragma unroll
    for (int nt = 0; nt < 8; nt++) {
      s8v bb = *(s8v*)&WoL[nt * 16 + l15][ks * 32 + kh * 8];
      acc[nt] = __builtin_amdgcn_mfma_f32_16x16x32_bf16(a, bb, acc[nt], 0, 0, 0);
    }
  }
  #pragma unroll
  for (int nt = 0; nt < 8; nt++) {
    int o = nt * 16 + l15;
    float bias = bo[o];
    int px0 = pbase + w * 16 + kh * 4;     // 4 consecutive pixels in regs 0..3
    float4 val = make_float4(acc[nt][0] + bias, acc[nt][1] + bias,
                             acc[nt][2] + bias, acc[nt][3] + bias);
    *(float4*)&out[((size_t)(b * 128 + o)) * 4096 + px0] = val;
  }
}

extern "C" void kernel_launch(void* const* d_in, const int* in_sizes, int n_in,
                              void* d_out, int out_size, void* d_ws, size_t ws_size,
                              hipStream_t stream) {
  (void)in_sizes; (void)n_in; (void)out_size; (void)ws_size;
  const float* x   = (const float*)d_in[0];
  const float* gw  = (const float*)d_in[1];
  const float* gb  = (const float*)d_in[2];
  const float* wq  = (const float*)d_in[3];
  const float* bq  = (const float*)d_in[4];
  const float* wk  = (const float*)d_in[5];
  const float* bk  = (const float*)d_in[6];
  const float* wv  = (const float*)d_in[7];
  const float* bv  = (const float*)d_in[8];
  const float* wo  = (const float*)d_in[9];
  const float* bo  = (const float*)d_in[10];
  const float* rpb = (const float*)d_in[11];
  float* ws    = (float*)d_ws;
  float* stats = ws + OFF_STATS;
  short* Wcb   = (short*)(ws + OFF_WCB);
  float* bc    = ws + OFF_BC;
  float* q     = ws + OFF_Q;
  float* kk    = ws + OFF_K;
  float* v     = ws + OFF_V;
  float* out   = (float*)d_out;
  float* xo    = out;  // aliased (see k4 comment)

  hipLaunchKernelGGL(k0_prep,  dim3(64),  dim3(256), 0, stream, wq, bq, wk, bk, wv, bv, Wcb, bc);
  hipLaunchKernelGGL(k1_stats, dim3(64),  dim3(256), 0, stream, x, stats);
  hipLaunchKernelGGL(k2_qkv,   dim3(512), dim3(256), 0, stream, x, stats, gw, gb, Wcb, bc, q);
  hipLaunchKernelGGL(k3_attn,  dim3(128), dim3(256), 0, stream, q, kk, v, rpb, xo);
  hipLaunchKernelGGL(k4_proj,  dim3(128), dim3(256), 0, stream, xo, wo, bo, out);
}

// Round 5
// 36.681 us; speedup vs baseline: 9.9610x; 3.5970x over previous
//
#include <hip/hip_runtime.h>

#define EPS 1e-5f

typedef short s8v __attribute__((ext_vector_type(8)));   // 8 bf16 in 4 VGPRs
typedef float f4v __attribute__((ext_vector_type(4)));

static __device__ inline short f2bf(float f) {
  return __builtin_bit_cast(short, (__bf16)f);
}

// workspace layout (float offsets)
#define OFF_STATS 0
#define OFF_WCB   128                     // bf16[384*128] = 49152 shorts = 24576 float slots
#define OFF_BC    (OFF_WCB + 24576)       // (round-4 bug: was +12288 -> bc overlapped Wcb)
#define OFF_QB    (OFF_BC + 384)          // bf16 [8][4096][32] = 524288 float slots
#define OFF_KB    (OFF_QB + 524288)
#define OFF_VTB   (OFF_KB + 524288)       // bf16 [8][32][4096] (transposed)

// K0: concat wq/wk/wv -> bf16 Wcb[384][128], fold q-scale into rows 0..127; bias stays fp32
__global__ void k0_prep(const float* __restrict__ wq, const float* __restrict__ bq,
                        const float* __restrict__ wk, const float* __restrict__ bk,
                        const float* __restrict__ wv, const float* __restrict__ bv,
                        short* __restrict__ Wcb, float* __restrict__ bc) {
  int t = blockIdx.x * 256 + threadIdx.x;   // 0..16383
  const float qs = 0.17677669529663687f;    // 1/sqrt(32)
  Wcb[t]         = f2bf(wq[t] * qs);
  Wcb[16384 + t] = f2bf(wk[t]);
  Wcb[32768 + t] = f2bf(wv[t]);
  if (t < 128) {
    bc[t]       = bq[t] * qs;
    bc[128 + t] = bk[t];
    bc[256 + t] = bv[t];
  }
}

// K1: GroupNorm stats, one block per (b, group)
__global__ __launch_bounds__(256) void k1_stats(const float* __restrict__ x,
                                                float* __restrict__ stats) {
  int g = blockIdx.x;  // 0..63
  const float4* xp = (const float4*)(x + (size_t)g * 16384);
  float s = 0.f, s2 = 0.f;
  for (int i = threadIdx.x; i < 4096; i += 256) {
    float4 v = xp[i];
    s  += v.x + v.y + v.z + v.w;
    s2 += v.x*v.x + v.y*v.y + v.z*v.z + v.w*v.w;
  }
  #pragma unroll
  for (int o = 32; o; o >>= 1) {
    s  += __shfl_down(s, o, 64);
    s2 += __shfl_down(s2, o, 64);
  }
  __shared__ float ls[4], ls2[4];
  int wid = threadIdx.x >> 6, lane = threadIdx.x & 63;
  if (!lane) { ls[wid] = s; ls2[wid] = s2; }
  __syncthreads();
  if (threadIdx.x == 0) {
    float S = 0.f, S2 = 0.f;
    #pragma unroll
    for (int i = 0; i < 4; i++) { S += ls[i]; S2 += ls2[i]; }
    float mean = S * (1.f / 16384.f);
    float var  = S2 * (1.f / 16384.f) - mean * mean;
    stats[g]      = mean;
    stats[64 + g] = rsqrtf(var + EPS);
  }
}

// K2: fused GN-normalize + QKV projection via MFMA; outputs bf16.
// Q,K: [bh][pix][32] bf16; V: transposed [bh][d][pix] bf16.
__global__ __launch_bounds__(256) void k2_qkv(
    const float* __restrict__ x, const float* __restrict__ stats,
    const float* __restrict__ gw, const float* __restrict__ gb,
    const short* __restrict__ Wcb, const float* __restrict__ bc,
    short* __restrict__ qb, short* __restrict__ kb, short* __restrict__ vtb) {
  __shared__ short xn[64][136];
  __shared__ short WL[96][136];
  int bid   = blockIdx.x;
  int ptile = bid >> 2, nslice = bid & 3;
  int b     = ptile >> 6;
  int pbase = (ptile & 63) * 64;
  int nbase = nslice * 96;
  int tid   = threadIdx.x;

  #pragma unroll
  for (int i = 0; i < 16; i++) {
    int e = tid + i * 256;
    int c2 = e >> 6, px = e & 63;
    int c0 = c2 * 2;
    int grp = b * 32 + (c0 >> 2);
    float mu = stats[grp], rs = stats[64 + grp];
    float v0 = x[((size_t)(b * 128 + c0))     * 4096 + pbase + px];
    float v1 = x[((size_t)(b * 128 + c0 + 1)) * 4096 + pbase + px];
    v0 = (v0 - mu) * rs * gw[c0]     + gb[c0];
    v1 = (v1 - mu) * rs * gw[c0 + 1] + gb[c0 + 1];
    xn[px][c0]     = f2bf(v0);
    xn[px][c0 + 1] = f2bf(v1);
  }
  #pragma unroll
  for (int i = 0; i < 6; i++) {
    int cc = tid + i * 256;
    int row = cc >> 4, c8 = (cc & 15) * 8;
    *(s8v*)&WL[row][c8] = *(const s8v*)&Wcb[(nbase + row) * 128 + c8];
  }
  __syncthreads();

  int w    = __builtin_amdgcn_readfirstlane(tid >> 6);
  int lane = tid & 63;
  int l15  = lane & 15, kh = lane >> 4;
  f4v acc[6];
  #pragma unroll
  for (int nt = 0; nt < 6; nt++) acc[nt] = (f4v){0.f, 0.f, 0.f, 0.f};
  #pragma unroll
  for (int ks = 0; ks < 4; ks++) {
    s8v a = *(s8v*)&xn[w * 16 + l15][ks * 32 + kh * 8];
    #pragma unroll
    for (int nt = 0; nt < 6; nt++) {
      s8v bb = *(s8v*)&WL[nt * 16 + l15][ks * 32 + kh * 8];
      acc[nt] = __builtin_amdgcn_mfma_f32_16x16x32_bf16(a, bb, acc[nt], 0, 0, 0);
    }
  }
  int px0 = pbase + w * 16 + kh * 4;
  #pragma unroll
  for (int nt = 0; nt < 6; nt++) {
    int o    = nbase + nt * 16 + l15;
    int mat  = o >> 7, rr = o & 127;
    int hd   = rr >> 5, d = rr & 31;
    int bh2  = b * 4 + hd;
    float bias = bc[o];
    if (mat == 2) {
      ushort s0 = (ushort)f2bf(acc[nt][0] + bias);
      ushort s1 = (ushort)f2bf(acc[nt][1] + bias);
      ushort s2 = (ushort)f2bf(acc[nt][2] + bias);
      ushort s3 = (ushort)f2bf(acc[nt][3] + bias);
      uint2 pk2 = make_uint2(((uint)s1 << 16) | s0, ((uint)s3 << 16) | s2);
      *(uint2*)&vtb[((size_t)bh2 * 32 + d) * 4096 + px0] = pk2;
    } else {
      short* dst = mat ? (short*)kb : (short*)qb;
      #pragma unroll
      for (int r = 0; r < 4; r++)
        dst[((size_t)bh2 * 4096 + px0 + r) * 32 + d] = f2bf(acc[nt][r] + bias);
    }
  }
}

// K3: MFMA neighborhood attention. Block = (bh, y-row): 4 waves, wave = 16-query strip.
// QK^T: A=K (m=kcol), B=Q (n=query) -> lane holds 8 logits of query l15.
// No-max online softmax (logits bounded ~1), P->bf16 via per-wave LDS row, PV MFMA.
// Writes xo in the reference's scrambled reshape layout (fp32).
__global__ __launch_bounds__(256) void k3_attn(
    const short* __restrict__ qb, const short* __restrict__ kb, const short* __restrict__ vtb,
    const float* __restrict__ rpb, float* __restrict__ xo) {
  __shared__ ushort K_s[7][64][32];     // [row][col][ch]
  __shared__ ushort VT_s[7][32][72];    // [row][d][col+pad]
  __shared__ ushort P_s[4][16][40];     // per-wave [q][kcol+pad]
  __shared__ float  rpb_s[169];
  int lb = blockIdx.x;
  int rb = ((lb & 7) << 6) | (lb >> 3);   // XCD swizzle: each XCD owns one bh
  int bh = rb >> 6, y = rb & 63;
  int head = bh & 3, b = bh >> 2;
  int tid = threadIdx.x;
  int ys = min(max(y - 3, 0), 57);

  {
    int col = tid >> 2, ch8 = (tid & 3) * 8;
    const size_t kbase = (size_t)bh * 4096 * 32;
    #pragma unroll
    for (int row = 0; row < 7; ++row)
      *(s8v*)&K_s[row][col][ch8] = *(const s8v*)&kb[kbase + (size_t)((ys + row) * 64 + col) * 32 + ch8];
  }
  {
    int d = tid >> 3, c8 = (tid & 7) * 8;
    const size_t vbase = (size_t)bh * 32 * 4096;
    #pragma unroll
    for (int row = 0; row < 7; ++row)
      *(s8v*)&VT_s[row][d][c8] = *(const s8v*)&vtb[vbase + (size_t)d * 4096 + (ys + row) * 64 + c8];
  }
  if (tid < 169) rpb_s[tid] = rpb[head * 169 + tid];
  __syncthreads();

  int w = __builtin_amdgcn_readfirstlane(tid >> 6);
  int lane = tid & 63, l15 = lane & 15, kh = lane >> 4;
  int c0 = w * 8 + (w >> 1) * 8;        // strip col window start: 0,8,24,32
  int xq = w * 16 + l15;                // query x
  int xs = min(max(xq - 3, 0), 57);
  int pbw = 3 + max(3 - xq, 0) + min(60 - xq, 0);
  int pbh = 3 + max(3 - y, 0) + min(60 - y, 0);

  s8v qf = *(const s8v*)&qb[((size_t)bh * 4096 + y * 64 + xq) * 32 + kh * 8];

  int   bidx[8];
  float badd[8];
  #pragma unroll
  for (int j = 0; j < 8; ++j) {
    int cc = (j >> 2) * 16 + kh * 4 + (j & 3);
    int dx = c0 + cc - xs;
    bool valid = (dx >= 0) && (dx < 7);
    bidx[j] = pbw + min(max(dx, 0), 6);
    badd[j] = valid ? 0.f : -1e30f;
  }

  const f4v zero = {0.f, 0.f, 0.f, 0.f};
  f4v o0 = zero, o1 = zero;
  float ssum = 0.f;

  #pragma unroll
  for (int row = 0; row < 7; ++row) {
    s8v ka0 = *(s8v*)&K_s[row][c0 + l15][kh * 8];
    s8v ka1 = *(s8v*)&K_s[row][c0 + 16 + l15][kh * 8];
    f4v lg0 = __builtin_amdgcn_mfma_f32_16x16x32_bf16(ka0, qf, zero, 0, 0, 0);
    f4v lg1 = __builtin_amdgcn_mfma_f32_16x16x32_bf16(ka1, qf, zero, 0, 0, 0);
    int rbase = (pbh + row) * 13;
    float p[8];
    #pragma unroll
    for (int j = 0; j < 4; ++j) {
      p[j]     = __expf(lg0[j] + rpb_s[rbase + bidx[j]]     + badd[j]);
      p[j + 4] = __expf(lg1[j] + rpb_s[rbase + bidx[j + 4]] + badd[j + 4]);
      ssum += p[j] + p[j + 4];
    }
    uint u0 = ((uint)(ushort)f2bf(p[1]) << 16) | (ushort)f2bf(p[0]);
    uint u1 = ((uint)(ushort)f2bf(p[3]) << 16) | (ushort)f2bf(p[2]);
    uint u2 = ((uint)(ushort)f2bf(p[5]) << 16) | (ushort)f2bf(p[4]);
    uint u3 = ((uint)(ushort)f2bf(p[7]) << 16) | (ushort)f2bf(p[6]);
    *(uint2*)&P_s[w][l15][kh * 4]      = make_uint2(u0, u1);
    *(uint2*)&P_s[w][l15][16 + kh * 4] = make_uint2(u2, u3);
    s8v pa  = *(s8v*)&P_s[w][l15][kh * 8];
    s8v vt0 = *(s8v*)&VT_s[row][l15][c0 + kh * 8];
    s8v vt1 = *(s8v*)&VT_s[row][16 + l15][c0 + kh * 8];
    o0 = __builtin_amdgcn_mfma_f32_16x16x32_bf16(pa, vt0, o0, 0, 0, 0);
    o1 = __builtin_amdgcn_mfma_f32_16x16x32_bf16(pa, vt1, o1, 0, 0, 0);
  }

  ssum += __shfl_xor(ssum, 16, 64);
  ssum += __shfl_xor(ssum, 32, 64);

  int spb = (head * 16 + (y >> 2)) * 64 + ((y & 3) << 4);
  #pragma unroll
  for (int r = 0; r < 4; ++r) {
    float sq = __builtin_bit_cast(float,
        __builtin_amdgcn_ds_bpermute((kh * 4 + r) << 2, __builtin_bit_cast(int, ssum)));
    float inv = 1.f / sq;
    int xp = w * 16 + kh * 4 + r;
    int cb = (xp & 3) * 32;
    int spx = spb + (xp >> 2);
    xo[((size_t)b * 128 + cb + l15) * 4096 + spx]      = o0[r] * inv;
    xo[((size_t)b * 128 + cb + 16 + l15) * 4096 + spx] = o1[r] * inv;
  }
}

// K4: output projection via MFMA (unchanged). xo aliases d_out.
__global__ __launch_bounds__(256) void k4_proj(
    const float* __restrict__ xo, const float* __restrict__ wo, const float* __restrict__ bo,
    float* __restrict__ out) {
  __shared__ short xs[64][136];
  __shared__ short WoL[128][136];
  int tile  = blockIdx.x;
  int b     = tile >> 6;
  int pbase = (tile & 63) * 64;
  int tid   = threadIdx.x;

  #pragma unroll
  for (int i = 0; i < 16; i++) {
    int e = tid + i * 256;
    int c2 = e >> 6, px = e & 63;
    int c0 = c2 * 2;
    xs[px][c0]     = f2bf(xo[((size_t)(b * 128 + c0))     * 4096 + pbase + px]);
    xs[px][c0 + 1] = f2bf(xo[((size_t)(b * 128 + c0 + 1)) * 4096 + pbase + px]);
  }
  #pragma unroll
  for (int i = 0; i < 8; i++) {
    int cc = tid + i * 256;
    int row = cc >> 4, c8 = (cc & 15) * 8;
    const float* src = wo + row * 128 + c8;
    float4 f0 = *(const float4*)src, f1 = *(const float4*)(src + 4);
    s8v wv8;
    wv8[0] = f2bf(f0.x); wv8[1] = f2bf(f0.y); wv8[2] = f2bf(f0.z); wv8[3] = f2bf(f0.w);
    wv8[4] = f2bf(f1.x); wv8[5] = f2bf(f1.y); wv8[6] = f2bf(f1.z); wv8[7] = f2bf(f1.w);
    *(s8v*)&WoL[row][c8] = wv8;
  }
  __syncthreads();

  int w    = __builtin_amdgcn_readfirstlane(tid >> 6);
  int lane = tid & 63;
  int l15  = lane & 15, kh = lane >> 4;
  f4v acc[8];
  #pragma unroll
  for (int nt = 0; nt < 8; nt++) acc[nt] = (f4v){0.f, 0.f, 0.f, 0.f};
  #pragma unroll
  for (int ks = 0; ks < 4; ks++) {
    s8v a = *(s8v*)&xs[w * 16 + l15][ks * 32 + kh * 8];
    #pragma unroll
    for (int nt = 0; nt < 8; nt++) {
      s8v bb = *(s8v*)&WoL[nt * 16 + l15][ks * 32 + kh * 8];
      acc[nt] = __builtin_amdgcn_mfma_f32_16x16x32_bf16(a, bb, acc[nt], 0, 0, 0);
    }
  }
  #pragma unroll
  for (int nt = 0; nt < 8; nt++) {
    int o = nt * 16 + l15;
    float bias = bo[o];
    int px0 = pbase + w * 16 + kh * 4;
    float4 val = make_float4(acc[nt][0] + bias, acc[nt][1] + bias,
                             acc[nt][2] + bias, acc[nt][3] + bias);
    *(float4*)&out[((size_t)(b * 128 + o)) * 4096 + px0] = val;
  }
}

extern "C" void kernel_launch(void* const* d_in, const int* in_sizes, int n_in,
                              void* d_out, int out_size, void* d_ws, size_t ws_size,
                              hipStream_t stream) {
  (void)in_sizes; (void)n_in; (void)out_size; (void)ws_size;
  const float* x   = (const float*)d_in[0];
  const float* gw  = (const float*)d_in[1];
  const float* gb  = (const float*)d_in[2];
  const float* wq  = (const float*)d_in[3];
  const float* bq  = (const float*)d_in[4];
  const float* wk  = (const float*)d_in[5];
  const float* bk  = (const float*)d_in[6];
  const float* wv  = (const float*)d_in[7];
  const float* bv  = (const float*)d_in[8];
  const float* wo  = (const float*)d_in[9];
  const float* bo  = (const float*)d_in[10];
  const float* rpb = (const float*)d_in[11];
  float* ws    = (float*)d_ws;
  float* stats = ws + OFF_STATS;
  short* Wcb   = (short*)(ws + OFF_WCB);
  float* bc    = ws + OFF_BC;
  short* qb    = (short*)(ws + OFF_QB);
  short* kb    = (short*)(ws + OFF_KB);
  short* vtb   = (short*)(ws + OFF_VTB);
  float* out   = (float*)d_out;
  float* xo    = out;  // aliased (k4 reads own pixels to LDS before overwriting)

  hipLaunchKernelGGL(k0_prep,  dim3(64),  dim3(256), 0, stream, wq, bq, wk, bk, wv, bv, Wcb, bc);
  hipLaunchKernelGGL(k1_stats, dim3(64),  dim3(256), 0, stream, x, stats);
  hipLaunchKernelGGL(k2_qkv,   dim3(512), dim3(256), 0, stream, x, stats, gw, gb, Wcb, bc, qb, kb, vtb);
  hipLaunchKernelGGL(k3_attn,  dim3(512), dim3(256), 0, stream, qb, kb, vtb, rpb, xo);
  hipLaunchKernelGGL(k4_proj,  dim3(128), dim3(256), 0, stream, xo, wo, bo, out);
}

// Round 6
// 34.992 us; speedup vs baseline: 10.4418x; 1.0483x over previous
//
#include <hip/hip_runtime.h>

#define EPS 1e-5f

typedef short s8v __attribute__((ext_vector_type(8)));   // 8 bf16 in 4 VGPRs
typedef float f4v __attribute__((ext_vector_type(4)));

static __device__ inline short f2bf(float f) {
  return __builtin_bit_cast(short, (__bf16)f);
}

// workspace layout (float offsets)
#define OFF_STATS 0
#define OFF_WCB   128                     // bf16[384*128] = 24576 float slots
#define OFF_BC    (OFF_WCB + 24576)
#define OFF_QB    (OFF_BC + 384)          // bf16 [8][4096][32]
#define OFF_KB    (OFF_QB + 524288)
#define OFF_VTB   (OFF_KB + 524288)       // bf16 [8][32][4096] (transposed)
#define OFF_WOB   (OFF_VTB + 524288)      // bf16 [128][128]

// KP: prep (blocks 0..63) + GroupNorm stats (blocks 64..127)
__global__ __launch_bounds__(256) void kP(
    const float* __restrict__ wq, const float* __restrict__ bq,
    const float* __restrict__ wk, const float* __restrict__ bk,
    const float* __restrict__ wv, const float* __restrict__ bv,
    const float* __restrict__ wo, const float* __restrict__ x,
    short* __restrict__ Wcb, float* __restrict__ bc,
    short* __restrict__ WoB, float* __restrict__ stats) {
  int blk = blockIdx.x;
  if (blk < 64) {
    int t = blk * 256 + threadIdx.x;        // 0..16383
    const float qs = 0.17677669529663687f;  // 1/sqrt(32)
    Wcb[t]         = f2bf(wq[t] * qs);
    Wcb[16384 + t] = f2bf(wk[t]);
    Wcb[32768 + t] = f2bf(wv[t]);
    WoB[t]         = f2bf(wo[t]);
    if (t < 128) {
      bc[t]       = bq[t] * qs;
      bc[128 + t] = bk[t];
      bc[256 + t] = bv[t];
    }
  } else {
    int g = blk - 64;  // 0..63
    const float4* xp = (const float4*)(x + (size_t)g * 16384);
    float s = 0.f, s2 = 0.f;
    for (int i = threadIdx.x; i < 4096; i += 256) {
      float4 v = xp[i];
      s  += v.x + v.y + v.z + v.w;
      s2 += v.x*v.x + v.y*v.y + v.z*v.z + v.w*v.w;
    }
    #pragma unroll
    for (int o = 32; o; o >>= 1) {
      s  += __shfl_down(s, o, 64);
      s2 += __shfl_down(s2, o, 64);
    }
    __shared__ float ls[4], ls2[4];
    int wid = threadIdx.x >> 6, lane = threadIdx.x & 63;
    if (!lane) { ls[wid] = s; ls2[wid] = s2; }
    __syncthreads();
    if (threadIdx.x == 0) {
      float S = 0.f, S2 = 0.f;
      #pragma unroll
      for (int i = 0; i < 4; i++) { S += ls[i]; S2 += ls2[i]; }
      float mean = S * (1.f / 16384.f);
      float var  = S2 * (1.f / 16384.f) - mean * mean;
      stats[g]      = mean;
      stats[64 + g] = rsqrtf(var + EPS);
    }
  }
}

// K2: fused GN-normalize + QKV projection via MFMA; outputs bf16.
// Q,K tiles use swapped operand order (A=W, B=x) so each lane holds 4
// consecutive d -> one packed uint2 store. V keeps original order
// (4 consecutive px per lane) -> uint2 store into transposed layout.
__global__ __launch_bounds__(256) void k2_qkv(
    const float* __restrict__ x, const float* __restrict__ stats,
    const float* __restrict__ gw, const float* __restrict__ gb,
    const short* __restrict__ Wcb, const float* __restrict__ bc,
    short* __restrict__ qb, short* __restrict__ kb, short* __restrict__ vtb) {
  __shared__ short xn[64][136];
  __shared__ short WL[96][136];
  __shared__ float bcs[96];
  int bid   = blockIdx.x;
  int ptile = bid >> 2, nslice = bid & 3;
  int b     = ptile >> 6;
  int pbase = (ptile & 63) * 64;
  int nbase = nslice * 96;
  int tid   = threadIdx.x;

  #pragma unroll
  for (int i = 0; i < 16; i++) {
    int e = tid + i * 256;
    int c2 = e >> 6, px = e & 63;
    int c0 = c2 * 2;
    int grp = b * 32 + (c0 >> 2);
    float mu = stats[grp], rs = stats[64 + grp];
    float v0 = x[((size_t)(b * 128 + c0))     * 4096 + pbase + px];
    float v1 = x[((size_t)(b * 128 + c0 + 1)) * 4096 + pbase + px];
    v0 = (v0 - mu) * rs * gw[c0]     + gb[c0];
    v1 = (v1 - mu) * rs * gw[c0 + 1] + gb[c0 + 1];
    xn[px][c0]     = f2bf(v0);
    xn[px][c0 + 1] = f2bf(v1);
  }
  #pragma unroll
  for (int i = 0; i < 6; i++) {
    int cc = tid + i * 256;
    int row = cc >> 4, c8 = (cc & 15) * 8;
    *(s8v*)&WL[row][c8] = *(const s8v*)&Wcb[(nbase + row) * 128 + c8];
  }
  if (tid < 96) bcs[tid] = bc[nbase + tid];
  __syncthreads();

  int w    = __builtin_amdgcn_readfirstlane(tid >> 6);
  int lane = tid & 63;
  int l15  = lane & 15, kh = lane >> 4;
  f4v acc[6];
  #pragma unroll
  for (int nt = 0; nt < 6; nt++) acc[nt] = (f4v){0.f, 0.f, 0.f, 0.f};
  #pragma unroll
  for (int ks = 0; ks < 4; ks++) {
    s8v a = *(s8v*)&xn[w * 16 + l15][ks * 32 + kh * 8];
    #pragma unroll
    for (int nt = 0; nt < 6; nt++) {
      s8v wf = *(s8v*)&WL[nt * 16 + l15][ks * 32 + kh * 8];
      if (nbase + nt * 16 < 256)   // q/k tile: swapped operands
        acc[nt] = __builtin_amdgcn_mfma_f32_16x16x32_bf16(wf, a, acc[nt], 0, 0, 0);
      else                          // v tile: original order
        acc[nt] = __builtin_amdgcn_mfma_f32_16x16x32_bf16(a, wf, acc[nt], 0, 0, 0);
    }
  }
  #pragma unroll
  for (int nt = 0; nt < 6; nt++) {
    if (nbase + nt * 16 < 256) {
      // lane holds o = nbase+nt*16+kh*4+r (r=0..3), px = pbase+w*16+l15
      int ob  = nt * 16 + kh * 4;
      int o0i = nbase + ob;
      int hd  = (o0i & 127) >> 5, d0 = o0i & 31;
      int bh2 = b * 4 + hd;
      int px  = pbase + w * 16 + l15;
      short* dst = (o0i >> 7) ? kb : qb;
      ushort e0 = (ushort)f2bf(acc[nt][0] + bcs[ob + 0]);
      ushort e1 = (ushort)f2bf(acc[nt][1] + bcs[ob + 1]);
      ushort e2 = (ushort)f2bf(acc[nt][2] + bcs[ob + 2]);
      ushort e3 = (ushort)f2bf(acc[nt][3] + bcs[ob + 3]);
      uint2 pk = make_uint2(((uint)e1 << 16) | e0, ((uint)e3 << 16) | e2);
      *(uint2*)&dst[((size_t)bh2 * 4096 + px) * 32 + d0] = pk;
    } else {
      // lane holds o = nbase+nt*16+l15, px = pbase+w*16+kh*4+r
      int o   = nbase + nt * 16 + l15;
      int hd  = (o & 127) >> 5, d = o & 31;
      int bh2 = b * 4 + hd;
      int px0 = pbase + w * 16 + kh * 4;
      float bias = bcs[nt * 16 + l15];
      ushort s0 = (ushort)f2bf(acc[nt][0] + bias);
      ushort s1 = (ushort)f2bf(acc[nt][1] + bias);
      ushort s2 = (ushort)f2bf(acc[nt][2] + bias);
      ushort s3 = (ushort)f2bf(acc[nt][3] + bias);
      uint2 pk2 = make_uint2(((uint)s1 << 16) | s0, ((uint)s3 << 16) | s2);
      *(uint2*)&vtb[((size_t)bh2 * 32 + d) * 4096 + px0] = pk2;
    }
  }
}

// K3: MFMA neighborhood attention + fused output projection.
// Block = (bh, y-row). Attention phase as round 5; then the block's full
// 128 c' x 16 px tile is staged in LDS (bf16), Wo staged into the dead
// K/V LDS region (union), out-proj via MFMA, coalesced float4 stores.
__global__ __launch_bounds__(256) void k3_attn_proj(
    const short* __restrict__ qb, const short* __restrict__ kb, const short* __restrict__ vtb,
    const float* __restrict__ rpb, const short* __restrict__ WoB,
    const float* __restrict__ bo, float* __restrict__ out) {
  struct PhA { ushort K[7][64][32]; ushort VT[7][32][72]; ushort P[4][16][40]; float rpb[172]; };
  struct PhB { ushort tile[16][136]; ushort Wo[128][136]; };
  __shared__ union { PhA a; PhB bb; } sm;

  int lb = blockIdx.x;
  int rb = ((lb & 7) << 6) | (lb >> 3);   // XCD swizzle: each XCD owns one bh
  int bh = rb >> 6, y = rb & 63;
  int head = bh & 3, b = bh >> 2;
  int tid = threadIdx.x;
  int ys = min(max(y - 3, 0), 57);

  {
    int col = tid >> 2, ch8 = (tid & 3) * 8;
    const size_t kbase = (size_t)bh * 4096 * 32;
    #pragma unroll
    for (int row = 0; row < 7; ++row)
      *(s8v*)&sm.a.K[row][col][ch8] = *(const s8v*)&kb[kbase + (size_t)((ys + row) * 64 + col) * 32 + ch8];
  }
  {
    int d = tid >> 3, c8 = (tid & 7) * 8;
    const size_t vbase = (size_t)bh * 32 * 4096;
    #pragma unroll
    for (int row = 0; row < 7; ++row)
      *(s8v*)&sm.a.VT[row][d][c8] = *(const s8v*)&vtb[vbase + (size_t)d * 4096 + (ys + row) * 64 + c8];
  }
  if (tid < 169) sm.a.rpb[tid] = rpb[head * 169 + tid];
  __syncthreads();

  int w = __builtin_amdgcn_readfirstlane(tid >> 6);
  int lane = tid & 63, l15 = lane & 15, kh = lane >> 4;
  int c0 = w * 8 + (w >> 1) * 8;        // strip col window start: 0,8,24,32
  int xq = w * 16 + l15;                // query x
  int xs = min(max(xq - 3, 0), 57);
  int pbw = 3 + max(3 - xq, 0) + min(60 - xq, 0);
  int pbh = 3 + max(3 - y, 0) + min(60 - y, 0);

  s8v qf = *(const s8v*)&qb[((size_t)bh * 4096 + y * 64 + xq) * 32 + kh * 8];

  int   bidx[8];
  float badd[8];
  #pragma unroll
  for (int j = 0; j < 8; ++j) {
    int cc = (j >> 2) * 16 + kh * 4 + (j & 3);
    int dx = c0 + cc - xs;
    bool valid = (dx >= 0) && (dx < 7);
    bidx[j] = pbw + min(max(dx, 0), 6);
    badd[j] = valid ? 0.f : -1e30f;
  }

  const f4v zero = {0.f, 0.f, 0.f, 0.f};
  f4v o0 = zero, o1 = zero;
  float ssum = 0.f;

  #pragma unroll
  for (int row = 0; row < 7; ++row) {
    s8v ka0 = *(s8v*)&sm.a.K[row][c0 + l15][kh * 8];
    s8v ka1 = *(s8v*)&sm.a.K[row][c0 + 16 + l15][kh * 8];
    f4v lg0 = __builtin_amdgcn_mfma_f32_16x16x32_bf16(ka0, qf, zero, 0, 0, 0);
    f4v lg1 = __builtin_amdgcn_mfma_f32_16x16x32_bf16(ka1, qf, zero, 0, 0, 0);
    int rbase = (pbh + row) * 13;
    float p[8];
    #pragma unroll
    for (int j = 0; j < 4; ++j) {
      p[j]     = __expf(lg0[j] + sm.a.rpb[rbase + bidx[j]]     + badd[j]);
      p[j + 4] = __expf(lg1[j] + sm.a.rpb[rbase + bidx[j + 4]] + badd[j + 4]);
      ssum += p[j] + p[j + 4];
    }
    uint u0 = ((uint)(ushort)f2bf(p[1]) << 16) | (ushort)f2bf(p[0]);
    uint u1 = ((uint)(ushort)f2bf(p[3]) << 16) | (ushort)f2bf(p[2]);
    uint u2 = ((uint)(ushort)f2bf(p[5]) << 16) | (ushort)f2bf(p[4]);
    uint u3 = ((uint)(ushort)f2bf(p[7]) << 16) | (ushort)f2bf(p[6]);
    *(uint2*)&sm.a.P[w][l15][kh * 4]      = make_uint2(u0, u1);
    *(uint2*)&sm.a.P[w][l15][16 + kh * 4] = make_uint2(u2, u3);
    s8v pa  = *(s8v*)&sm.a.P[w][l15][kh * 8];
    s8v vt0 = *(s8v*)&sm.a.VT[row][l15][c0 + kh * 8];
    s8v vt1 = *(s8v*)&sm.a.VT[row][16 + l15][c0 + kh * 8];
    o0 = __builtin_amdgcn_mfma_f32_16x16x32_bf16(pa, vt0, o0, 0, 0, 0);
    o1 = __builtin_amdgcn_mfma_f32_16x16x32_bf16(pa, vt1, o1, 0, 0, 0);
  }

  ssum += __shfl_xor(ssum, 16, 64);
  ssum += __shfl_xor(ssum, 32, 64);

  __syncthreads();   // all waves done reading K/VT/P -> safe to overlay

  // stage Wo (128x128 bf16) into union region
  #pragma unroll
  for (int i = 0; i < 8; i++) {
    int cc = tid + i * 256;
    int row = cc >> 4, c8 = (cc & 15) * 8;
    *(s8v*)&sm.bb.Wo[row][c8] = *(const s8v*)&WoB[row * 128 + c8];
  }
  // write attention tile: lane (l15,kh) of wave w holds, for r=0..3:
  //   c' = r*32 + l15 (o0) and r*32 + 16 + l15 (o1); px col = w*4 + kh
  {
    int col = w * 4 + kh;
    #pragma unroll
    for (int r = 0; r < 4; ++r) {
      float sq = __builtin_bit_cast(float,
          __builtin_amdgcn_ds_bpermute((kh * 4 + r) << 2, __builtin_bit_cast(int, ssum)));
      float inv = 1.f / sq;
      sm.bb.tile[col][r * 32 + l15]      = (ushort)f2bf(o0[r] * inv);
      sm.bb.tile[col][r * 32 + 16 + l15] = (ushort)f2bf(o1[r] * inv);
    }
  }
  __syncthreads();

  // out-projection: wave w owns outputs o = w*32 + nt*16 + l15 (nt=0,1);
  // A = tile[px=l15][c], B = Wo[o][c]; D: px = kh*4+r, o = l15 (k4-verified map)
  f4v acc2[2];
  acc2[0] = zero; acc2[1] = zero;
  #pragma unroll
  for (int ks = 0; ks < 4; ks++) {
    s8v a = *(s8v*)&sm.bb.tile[l15][ks * 32 + kh * 8];
    #pragma unroll
    for (int nt = 0; nt < 2; nt++) {
      s8v bf = *(s8v*)&sm.bb.Wo[w * 32 + nt * 16 + l15][ks * 32 + kh * 8];
      acc2[nt] = __builtin_amdgcn_mfma_f32_16x16x32_bf16(a, bf, acc2[nt], 0, 0, 0);
    }
  }
  int pxg = (head * 16 + (y >> 2)) * 64 + ((y & 3) << 4);
  #pragma unroll
  for (int nt = 0; nt < 2; nt++) {
    int o = w * 32 + nt * 16 + l15;
    float bias = bo[o];
    float4 val = make_float4(acc2[nt][0] + bias, acc2[nt][1] + bias,
                             acc2[nt][2] + bias, acc2[nt][3] + bias);
    *(float4*)&out[((size_t)b * 128 + o) * 4096 + pxg + kh * 4] = val;
  }
}

extern "C" void kernel_launch(void* const* d_in, const int* in_sizes, int n_in,
                              void* d_out, int out_size, void* d_ws, size_t ws_size,
                              hipStream_t stream) {
  (void)in_sizes; (void)n_in; (void)out_size; (void)ws_size;
  const float* x   = (const float*)d_in[0];
  const float* gw  = (const float*)d_in[1];
  const float* gb  = (const float*)d_in[2];
  const float* wq  = (const float*)d_in[3];
  const float* bq  = (const float*)d_in[4];
  const float* wk  = (const float*)d_in[5];
  const float* bk  = (const float*)d_in[6];
  const float* wv  = (const float*)d_in[7];
  const float* bv  = (const float*)d_in[8];
  const float* wo  = (const float*)d_in[9];
  const float* bo  = (const float*)d_in[10];
  const float* rpb = (const float*)d_in[11];
  float* ws    = (float*)d_ws;
  float* stats = ws + OFF_STATS;
  short* Wcb   = (short*)(ws + OFF_WCB);
  float* bc    = ws + OFF_BC;
  short* qb    = (short*)(ws + OFF_QB);
  short* kb    = (short*)(ws + OFF_KB);
  short* vtb   = (short*)(ws + OFF_VTB);
  short* WoB   = (short*)(ws + OFF_WOB);
  float* out   = (float*)d_out;

  hipLaunchKernelGGL(kP, dim3(128), dim3(256), 0, stream,
                     wq, bq, wk, bk, wv, bv, wo, x, Wcb, bc, WoB, stats);
  hipLaunchKernelGGL(k2_qkv, dim3(512), dim3(256), 0, stream,
                     x, stats, gw, gb, Wcb, bc, qb, kb, vtb);
  hipLaunchKernelGGL(k3_attn_proj, dim3(512), dim3(256), 0, stream,
                     qb, kb, vtb, rpb, WoB, bo, out);
}

// Round 7
// 32.362 us; speedup vs baseline: 11.2905x; 1.0813x over previous
//
#include <hip/hip_runtime.h>

#define EPS 1e-5f

typedef short s8v __attribute__((ext_vector_type(8)));   // 8 bf16 in 4 VGPRs
typedef float f4v __attribute__((ext_vector_type(4)));

static __device__ inline short f2bf(float f) {
  return __builtin_bit_cast(short, (__bf16)f);
}

// workspace layout (float offsets)
#define OFF_S     0                       // sArr[256]  (gamma*rs per b,c)
#define OFF_T     256                     // tArr[256]  (beta - mu*gamma*rs)
#define OFF_WCB   512                     // bf16[384*128] = 24576 float slots
#define OFF_BC    (OFF_WCB + 24576)       // 384
#define OFF_QB    (OFF_BC + 384)          // bf16 [8][4096][32]
#define OFF_KB    (OFF_QB + 524288)
#define OFF_VTB   (OFF_KB + 524288)       // bf16 [8][32][4096] (transposed)
#define OFF_WOB   (OFF_VTB + 524288)      // bf16 [128][128]

// KP: blocks 0..63 = weight prep; blocks 64..127 = GN stats -> per-channel affine (s,t)
__global__ __launch_bounds__(256) void kP(
    const float* __restrict__ wq, const float* __restrict__ bq,
    const float* __restrict__ wk, const float* __restrict__ bk,
    const float* __restrict__ wv, const float* __restrict__ bv,
    const float* __restrict__ wo, const float* __restrict__ gw,
    const float* __restrict__ gb, const float* __restrict__ x,
    short* __restrict__ Wcb, float* __restrict__ bc,
    short* __restrict__ WoB, float* __restrict__ sArr, float* __restrict__ tArr) {
  int blk = blockIdx.x;
  if (blk < 64) {
    int t = blk * 256 + threadIdx.x;        // 0..16383
    const float qs = 0.17677669529663687f;  // 1/sqrt(32)
    Wcb[t]         = f2bf(wq[t] * qs);
    Wcb[16384 + t] = f2bf(wk[t]);
    Wcb[32768 + t] = f2bf(wv[t]);
    WoB[t]         = f2bf(wo[t]);
    if (t < 128) {
      bc[t]       = bq[t] * qs;
      bc[128 + t] = bk[t];
      bc[256 + t] = bv[t];
    }
  } else {
    int g = blk - 64;  // 0..63 = b*32+grp
    const float4* xp = (const float4*)(x + (size_t)g * 16384);
    float s = 0.f, s2 = 0.f;
    for (int i = threadIdx.x; i < 4096; i += 256) {
      float4 v = xp[i];
      s  += v.x + v.y + v.z + v.w;
      s2 += v.x*v.x + v.y*v.y + v.z*v.z + v.w*v.w;
    }
    #pragma unroll
    for (int o = 32; o; o >>= 1) {
      s  += __shfl_down(s, o, 64);
      s2 += __shfl_down(s2, o, 64);
    }
    __shared__ float ls[4], ls2[4];
    int wid = threadIdx.x >> 6, lane = threadIdx.x & 63;
    if (!lane) { ls[wid] = s; ls2[wid] = s2; }
    __syncthreads();
    if (threadIdx.x == 0) {
      float S = 0.f, S2 = 0.f;
      #pragma unroll
      for (int i = 0; i < 4; i++) { S += ls[i]; S2 += ls2[i]; }
      float mean = S * (1.f / 16384.f);
      float var  = S2 * (1.f / 16384.f) - mean * mean;
      float rsv  = rsqrtf(var + EPS);
      int b = g >> 5, grp = g & 31;
      #pragma unroll
      for (int j = 0; j < 4; j++) {
        int c = grp * 4 + j;
        float sv = rsv * gw[c];
        sArr[b * 128 + c] = sv;
        tArr[b * 128 + c] = gb[c] - mean * sv;
      }
    }
  }
}

// K2: fused GN-affine + QKV projection via MFMA; outputs bf16.
// 256 blocks = 128 pixel-tiles x 2 n-slices (192 outputs). Wave: 16px x 12 N-tiles.
// Q,K tiles use swapped operands (A=W, B=x) -> lane holds 4 consecutive d -> uint2 store.
// V tiles original order -> 4 consecutive px -> uint2 store into transposed layout.
__global__ __launch_bounds__(256) void k2_qkv(
    const float* __restrict__ x, const float* __restrict__ sArr, const float* __restrict__ tArr,
    const short* __restrict__ Wcb, const float* __restrict__ bc,
    short* __restrict__ qb, short* __restrict__ kb, short* __restrict__ vtb) {
  __shared__ short xn[64][136];
  __shared__ short WL[192][136];
  __shared__ float bcs[192];
  int bid    = blockIdx.x;          // 0..255
  int ptile  = bid >> 1, nslice = bid & 1;
  int b      = ptile >> 6;
  int pbase  = (ptile & 63) * 64;
  int nbase  = nslice * 192;
  int tid    = threadIdx.x;
  int w      = __builtin_amdgcn_readfirstlane(tid >> 6);
  int lane   = tid & 63;

  // stage GN-affine x tile: xn = f2bf(x*s + t); channel pair per iter, wave-uniform c
  #pragma unroll
  for (int i = 0; i < 16; i++) {
    int c0 = (w + i * 4) * 2;
    float s0 = sArr[b * 128 + c0],     t0 = tArr[b * 128 + c0];
    float s1 = sArr[b * 128 + c0 + 1], t1 = tArr[b * 128 + c0 + 1];
    float v0 = x[((size_t)(b * 128 + c0))     * 4096 + pbase + lane];
    float v1 = x[((size_t)(b * 128 + c0 + 1)) * 4096 + pbase + lane];
    ushort e0 = (ushort)f2bf(fmaf(v0, s0, t0));
    ushort e1 = (ushort)f2bf(fmaf(v1, s1, t1));
    *(uint*)&xn[lane][c0] = ((uint)e1 << 16) | e0;
  }
  #pragma unroll
  for (int i = 0; i < 12; i++) {
    int cc = tid + i * 256;          // 0..3071
    int row = cc >> 4, c8 = (cc & 15) * 8;
    *(s8v*)&WL[row][c8] = *(const s8v*)&Wcb[(nbase + row) * 128 + c8];
  }
  if (tid < 192) bcs[tid] = bc[nbase + tid];
  __syncthreads();

  int l15 = lane & 15, kh = lane >> 4;
  f4v acc[12];
  #pragma unroll
  for (int nt = 0; nt < 12; nt++) acc[nt] = (f4v){0.f, 0.f, 0.f, 0.f};
  #pragma unroll
  for (int ks = 0; ks < 4; ks++) {
    s8v a = *(s8v*)&xn[w * 16 + l15][ks * 32 + kh * 8];
    #pragma unroll
    for (int nt = 0; nt < 12; nt++) {
      s8v wf = *(s8v*)&WL[nt * 16 + l15][ks * 32 + kh * 8];
      if (nbase + nt * 16 < 256)    // q/k tile: swapped operands
        acc[nt] = __builtin_amdgcn_mfma_f32_16x16x32_bf16(wf, a, acc[nt], 0, 0, 0);
      else                           // v tile
        acc[nt] = __builtin_amdgcn_mfma_f32_16x16x32_bf16(a, wf, acc[nt], 0, 0, 0);
    }
  }
  #pragma unroll
  for (int nt = 0; nt < 12; nt++) {
    if (nbase + nt * 16 < 256) {
      // lane holds o = nbase+nt*16+kh*4+r, px = pbase+w*16+l15
      int ob  = nt * 16 + kh * 4;
      int o0i = nbase + ob;
      int hd  = (o0i & 127) >> 5, d0 = o0i & 31;
      int bh2 = b * 4 + hd;
      int px  = pbase + w * 16 + l15;
      short* dst = (o0i >> 7) ? kb : qb;
      ushort e0 = (ushort)f2bf(acc[nt][0] + bcs[ob + 0]);
      ushort e1 = (ushort)f2bf(acc[nt][1] + bcs[ob + 1]);
      ushort e2 = (ushort)f2bf(acc[nt][2] + bcs[ob + 2]);
      ushort e3 = (ushort)f2bf(acc[nt][3] + bcs[ob + 3]);
      uint2 pk = make_uint2(((uint)e1 << 16) | e0, ((uint)e3 << 16) | e2);
      *(uint2*)&dst[((size_t)bh2 * 4096 + px) * 32 + d0] = pk;
    } else {
      // lane holds o = nbase+nt*16+l15, px = pbase+w*16+kh*4+r
      int o   = nbase + nt * 16 + l15;
      int hd  = (o & 127) >> 5, d = o & 31;
      int bh2 = b * 4 + hd;
      int px0 = pbase + w * 16 + kh * 4;
      float bias = bcs[nt * 16 + l15];
      ushort s0 = (ushort)f2bf(acc[nt][0] + bias);
      ushort s1 = (ushort)f2bf(acc[nt][1] + bias);
      ushort s2 = (ushort)f2bf(acc[nt][2] + bias);
      ushort s3 = (ushort)f2bf(acc[nt][3] + bias);
      uint2 pk2 = make_uint2(((uint)s1 << 16) | s0, ((uint)s3 << 16) | s2);
      *(uint2*)&vtb[((size_t)bh2 * 32 + d) * 4096 + px0] = pk2;
    }
  }
}

// K3: MFMA neighborhood attention + fused out-projection, 2 query rows per block.
// 256 blocks (bh, y-chunk of 2) x 512 threads (8 waves): waves 0-3 row y0, 4-7 row y0+1.
// Shared 8-row K/VT window staged once (rows overlap 6/7). Phase B overlays LDS (union)
// with the 2-row attention tile + Wo, out-proj via MFMA, coalesced float4 stores.
__global__ __launch_bounds__(512) void k3_attn_proj(
    const short* __restrict__ qb, const short* __restrict__ kb, const short* __restrict__ vtb,
    const float* __restrict__ rpb, const short* __restrict__ WoB,
    const float* __restrict__ bo, float* __restrict__ out) {
  struct PhA { ushort K[8][64][32]; ushort VT[8][32][68]; ushort P[8][16][40]; float rpb[176]; };
  struct PhB { ushort tile[2][16][136]; ushort Wo[128][136]; };
  __shared__ union { PhA a; PhB bb; } sm;

  int lb    = blockIdx.x;           // 0..255
  int bh    = lb & 7;               // XCD swizzle: each XCD owns one bh
  int chunk = lb >> 3;              // 0..31
  int y0    = chunk * 2;
  int head  = bh & 3, b = bh >> 2;
  int tid   = threadIdx.x;
  int w     = __builtin_amdgcn_readfirstlane(tid >> 6);  // 0..7
  int lane  = tid & 63, l15 = lane & 15, kh = lane >> 4;
  int wsub  = w & 3, rsel = w >> 2;
  int y     = y0 + rsel;
  int ys0   = min(max(y0 - 3, 0), 57);
  int ysoff = min(max(y - 3, 0), 57) - ys0;   // 0 or 1

  // stage K window (8 rows x 64 col x 32 ch bf16)
  {
    const size_t kbase = (size_t)bh * 4096 * 32;
    #pragma unroll
    for (int i = 0; i < 4; i++) {
      int cc = tid + i * 512;
      int row = cc >> 8, rem = cc & 255;
      int col = rem >> 2, ch8 = (rem & 3) * 8;
      int yr = min(ys0 + row, 63);
      *(s8v*)&sm.a.K[row][col][ch8] = *(const s8v*)&kb[kbase + (size_t)(yr * 64 + col) * 32 + ch8];
    }
  }
  // stage VT window (8 rows x 32 d x 64 px bf16)
  {
    const size_t vbase = (size_t)bh * 32 * 4096;
    #pragma unroll
    for (int i = 0; i < 4; i++) {
      int cc = tid + i * 512;
      int row = cc >> 8, rem = cc & 255;
      int d = rem >> 3, c8 = (rem & 7) * 8;
      int yr = min(ys0 + row, 63);
      *(s8v*)&sm.a.VT[row][d][c8] = *(const s8v*)&vtb[vbase + (size_t)d * 4096 + yr * 64 + c8];
    }
  }
  if (tid < 169) sm.a.rpb[tid] = rpb[head * 169 + tid];
  __syncthreads();

  int c0  = wsub * 8 + (wsub >> 1) * 8;   // strip col window start: 0,8,24,32
  int xq  = wsub * 16 + l15;              // query x
  int xs  = min(max(xq - 3, 0), 57);
  int pbw = 3 + max(3 - xq, 0) + min(60 - xq, 0);
  int pbh = 3 + max(3 - y, 0) + min(60 - y, 0);

  s8v qf = *(const s8v*)&qb[((size_t)bh * 4096 + y * 64 + xq) * 32 + kh * 8];

  int   bidx[8];
  float badd[8];
  #pragma unroll
  for (int j = 0; j < 8; ++j) {
    int cc = (j >> 2) * 16 + kh * 4 + (j & 3);
    int dx = c0 + cc - xs;
    bool valid = (dx >= 0) && (dx < 7);
    bidx[j] = pbw + min(max(dx, 0), 6);
    badd[j] = valid ? 0.f : -1e30f;
  }

  const f4v zero = {0.f, 0.f, 0.f, 0.f};
  f4v o0 = zero, o1 = zero;
  float ssum = 0.f;

  #pragma unroll
  for (int row = 0; row < 7; ++row) {
    int kr = ysoff + row;
    s8v ka0 = *(s8v*)&sm.a.K[kr][c0 + l15][kh * 8];
    s8v ka1 = *(s8v*)&sm.a.K[kr][c0 + 16 + l15][kh * 8];
    f4v lg0 = __builtin_amdgcn_mfma_f32_16x16x32_bf16(ka0, qf, zero, 0, 0, 0);
    f4v lg1 = __builtin_amdgcn_mfma_f32_16x16x32_bf16(ka1, qf, zero, 0, 0, 0);
    int rbase = (pbh + row) * 13;
    float p[8];
    #pragma unroll
    for (int j = 0; j < 4; ++j) {
      p[j]     = __expf(lg0[j] + sm.a.rpb[rbase + bidx[j]]     + badd[j]);
      p[j + 4] = __expf(lg1[j] + sm.a.rpb[rbase + bidx[j + 4]] + badd[j + 4]);
      ssum += p[j] + p[j + 4];
    }
    uint u0 = ((uint)(ushort)f2bf(p[1]) << 16) | (ushort)f2bf(p[0]);
    uint u1 = ((uint)(ushort)f2bf(p[3]) << 16) | (ushort)f2bf(p[2]);
    uint u2 = ((uint)(ushort)f2bf(p[5]) << 16) | (ushort)f2bf(p[4]);
    uint u3 = ((uint)(ushort)f2bf(p[7]) << 16) | (ushort)f2bf(p[6]);
    *(uint2*)&sm.a.P[w][l15][kh * 4]      = make_uint2(u0, u1);
    *(uint2*)&sm.a.P[w][l15][16 + kh * 4] = make_uint2(u2, u3);
    s8v pa  = *(s8v*)&sm.a.P[w][l15][kh * 8];
    s8v vt0 = *(s8v*)&sm.a.VT[kr][l15][c0 + kh * 8];
    s8v vt1 = *(s8v*)&sm.a.VT[kr][16 + l15][c0 + kh * 8];
    o0 = __builtin_amdgcn_mfma_f32_16x16x32_bf16(pa, vt0, o0, 0, 0, 0);
    o1 = __builtin_amdgcn_mfma_f32_16x16x32_bf16(pa, vt1, o1, 0, 0, 0);
  }

  ssum += __shfl_xor(ssum, 16, 64);
  ssum += __shfl_xor(ssum, 32, 64);

  __syncthreads();   // all waves done with K/VT/P -> safe to overlay

  // stage Wo (128x128 bf16)
  #pragma unroll
  for (int i = 0; i < 4; i++) {
    int cc = tid + i * 512;
    int row = cc >> 4, c8 = (cc & 15) * 8;
    *(s8v*)&sm.bb.Wo[row][c8] = *(const s8v*)&WoB[row * 128 + c8];
  }
  // write attention tile: lane (l15,kh) holds O[query=kh*4+r][d=l15(,+16)];
  // within-row px col = wsub*4 + kh, c' = r*32 + d
  {
    int col = wsub * 4 + kh;
    #pragma unroll
    for (int r = 0; r < 4; ++r) {
      float sq = __builtin_bit_cast(float,
          __builtin_amdgcn_ds_bpermute((kh * 4 + r) << 2, __builtin_bit_cast(int, ssum)));
      float inv = 1.f / sq;
      sm.bb.tile[rsel][col][r * 32 + l15]      = (ushort)f2bf(o0[r] * inv);
      sm.bb.tile[rsel][col][r * 32 + 16 + l15] = (ushort)f2bf(o1[r] * inv);
    }
  }
  __syncthreads();

  // out-projection: wave (wsub,rsel) owns outputs o = wsub*32 + nt*16 + l15 for its row
  f4v acc2[2];
  acc2[0] = zero; acc2[1] = zero;
  #pragma unroll
  for (int ks = 0; ks < 4; ks++) {
    s8v a = *(s8v*)&sm.bb.tile[rsel][l15][ks * 32 + kh * 8];
    #pragma unroll
    for (int nt = 0; nt < 2; nt++) {
      s8v bf = *(s8v*)&sm.bb.Wo[wsub * 32 + nt * 16 + l15][ks * 32 + kh * 8];
      acc2[nt] = __builtin_amdgcn_mfma_f32_16x16x32_bf16(a, bf, acc2[nt], 0, 0, 0);
    }
  }
  int pxg = (head * 16 + (y >> 2)) * 64 + ((y & 3) << 4);
  #pragma unroll
  for (int nt = 0; nt < 2; nt++) {
    int o = wsub * 32 + nt * 16 + l15;
    float bias = bo[o];
    float4 val = make_float4(acc2[nt][0] + bias, acc2[nt][1] + bias,
                             acc2[nt][2] + bias, acc2[nt][3] + bias);
    *(float4*)&out[((size_t)b * 128 + o) * 4096 + pxg + kh * 4] = val;
  }
}

extern "C" void kernel_launch(void* const* d_in, const int* in_sizes, int n_in,
                              void* d_out, int out_size, void* d_ws, size_t ws_size,
                              hipStream_t stream) {
  (void)in_sizes; (void)n_in; (void)out_size; (void)ws_size;
  const float* x   = (const float*)d_in[0];
  const float* gw  = (const float*)d_in[1];
  const float* gb  = (const float*)d_in[2];
  const float* wq  = (const float*)d_in[3];
  const float* bq  = (const float*)d_in[4];
  const float* wk  = (const float*)d_in[5];
  const float* bk  = (const float*)d_in[6];
  const float* wv  = (const float*)d_in[7];
  const float* bv  = (const float*)d_in[8];
  const float* wo  = (const float*)d_in[9];
  const float* bo  = (const float*)d_in[10];
  const float* rpb = (const float*)d_in[11];
  float* ws    = (float*)d_ws;
  float* sArr  = ws + OFF_S;
  float* tArr  = ws + OFF_T;
  short* Wcb   = (short*)(ws + OFF_WCB);
  float* bc    = ws + OFF_BC;
  short* qb    = (short*)(ws + OFF_QB);
  short* kb    = (short*)(ws + OFF_KB);
  short* vtb   = (short*)(ws + OFF_VTB);
  short* WoB   = (short*)(ws + OFF_WOB);
  float* out   = (float*)d_out;

  hipLaunchKernelGGL(kP, dim3(128), dim3(256), 0, stream,
                     wq, bq, wk, bk, wv, bv, wo, gw, gb, x, Wcb, bc, WoB, sArr, tArr);
  hipLaunchKernelGGL(k2_qkv, dim3(256), dim3(256), 0, stream,
                     x, sArr, tArr, Wcb, bc, qb, kb, vtb);
  hipLaunchKernelGGL(k3_attn_proj, dim3(256), dim3(512), 0, stream,
                     qb, kb, vtb, rpb, WoB, bo, out);
}

// Round 8
// 26.961 us; speedup vs baseline: 13.5520x; 1.2003x over previous
//
#include <hip/hip_runtime.h>

#define EPS 1e-5f

typedef short s8v __attribute__((ext_vector_type(8)));   // 8 bf16 in 4 VGPRs
typedef float f4v __attribute__((ext_vector_type(4)));

static __device__ inline short f2bf(float f) {
  return __builtin_bit_cast(short, (__bf16)f);
}

// workspace layout (float offsets)
#define OFF_SP    0                       // Spart[256]  (64 groups x 4 partials)
#define OFF_S2P   256                     // S2part[256]
#define OFF_WCB   512                     // bf16[384*128] = 24576 float slots
#define OFF_BC    (OFF_WCB + 24576)       // 384
#define OFF_QB    (OFF_BC + 384)          // bf16 [8][4096][32]
#define OFF_KB    (OFF_QB + 524288)
#define OFF_VTB   (OFF_KB + 524288)       // bf16 [8][32][4096] (transposed)
#define OFF_WOB   (OFF_VTB + 524288)      // bf16 [128][128]

// KP: blocks 0..63 = weight prep; blocks 64..319 = GN partial sums (atomic-free:
// each (group, quarter) writes its own slot; k2 finalizes).
__global__ __launch_bounds__(256) void kP(
    const float* __restrict__ wq, const float* __restrict__ bq,
    const float* __restrict__ wk, const float* __restrict__ bk,
    const float* __restrict__ wv, const float* __restrict__ bv,
    const float* __restrict__ wo, const float* __restrict__ x,
    short* __restrict__ Wcb, float* __restrict__ bc,
    short* __restrict__ WoB, float* __restrict__ Spart, float* __restrict__ S2part) {
  int blk = blockIdx.x;
  int tid = threadIdx.x;
  if (blk < 64) {
    int t = blk * 256 + tid;                // 0..16383
    const float qs = 0.17677669529663687f;  // 1/sqrt(32)
    Wcb[t]         = f2bf(wq[t] * qs);
    Wcb[16384 + t] = f2bf(wk[t]);
    Wcb[32768 + t] = f2bf(wv[t]);
    WoB[t]         = f2bf(wo[t]);
    if (t < 128) {
      bc[t]       = bq[t] * qs;
      bc[128 + t] = bk[t];
      bc[256 + t] = bv[t];
    }
  } else {
    int idx = blk - 64;                     // 0..255
    int g = idx >> 2, part = idx & 3;       // group 0..63, quarter 0..3
    const float4* xp = (const float4*)(x + (size_t)g * 16384 + part * 4096);
    float s = 0.f, s2 = 0.f;
    #pragma unroll
    for (int i = 0; i < 4; i++) {
      float4 v = xp[tid + i * 256];
      s  += v.x + v.y + v.z + v.w;
      s2 += v.x*v.x + v.y*v.y + v.z*v.z + v.w*v.w;
    }
    #pragma unroll
    for (int o = 32; o; o >>= 1) {
      s  += __shfl_down(s, o, 64);
      s2 += __shfl_down(s2, o, 64);
    }
    __shared__ float ls[4], ls2[4];
    int wid = tid >> 6, lane = tid & 63;
    if (!lane) { ls[wid] = s; ls2[wid] = s2; }
    __syncthreads();
    if (tid == 0) {
      float S = 0.f, S2 = 0.f;
      #pragma unroll
      for (int i = 0; i < 4; i++) { S += ls[i]; S2 += ls2[i]; }
      Spart[idx]  = S;
      S2part[idx] = S2;
    }
  }
}

// K2: GN finalize + affine + QKV projection via MFMA; outputs bf16.
// 256 blocks = 128 pixel-tiles x 2 n-slices (192 outputs). Wave: 16px x 12 N-tiles.
// All global loads issued up front; affine computed in-block; one barrier; pack; MFMA.
__global__ __launch_bounds__(256) void k2_qkv(
    const float* __restrict__ x,
    const float* __restrict__ Spart, const float* __restrict__ S2part,
    const float* __restrict__ gw, const float* __restrict__ gb,
    const short* __restrict__ Wcb, const float* __restrict__ bc,
    short* __restrict__ qb, short* __restrict__ kb, short* __restrict__ vtb) {
  __shared__ short xn[64][136];
  __shared__ short WL[192][136];
  __shared__ float bcs[192];
  __shared__ float sm_s[128], sm_t[128];
  int bid    = blockIdx.x;          // 0..255
  int ptile  = bid >> 1, nslice = bid & 1;
  int b      = ptile >> 6;
  int pbase  = (ptile & 63) * 64;
  int nbase  = nslice * 192;
  int tid    = threadIdx.x;
  int w      = __builtin_amdgcn_readfirstlane(tid >> 6);
  int lane   = tid & 63;

  // issue all x loads into registers (latency hides under staging below)
  float va[16], vb[16];
  #pragma unroll
  for (int i = 0; i < 16; i++) {
    int c0 = (w + i * 4) * 2;
    va[i] = x[((size_t)(b * 128 + c0))     * 4096 + pbase + lane];
    vb[i] = x[((size_t)(b * 128 + c0 + 1)) * 4096 + pbase + lane];
  }
  // GN finalize -> per-channel affine in LDS
  if (tid < 128) {
    int c = tid, gi = (b * 32 + (c >> 2)) * 4;
    float S  = Spart[gi]  + Spart[gi + 1]  + Spart[gi + 2]  + Spart[gi + 3];
    float S2 = S2part[gi] + S2part[gi + 1] + S2part[gi + 2] + S2part[gi + 3];
    float mean = S * (1.f / 16384.f);
    float var  = S2 * (1.f / 16384.f) - mean * mean;
    float sv   = rsqrtf(var + EPS) * gw[c];
    sm_s[c] = sv;
    sm_t[c] = gb[c] - mean * sv;
  }
  // stage weights + biases
  #pragma unroll
  for (int i = 0; i < 12; i++) {
    int cc = tid + i * 256;          // 0..3071
    int row = cc >> 4, c8 = (cc & 15) * 8;
    *(s8v*)&WL[row][c8] = *(const s8v*)&Wcb[(nbase + row) * 128 + c8];
  }
  if (tid < 192) bcs[tid] = bc[nbase + tid];
  __syncthreads();   // affine visible

  // pack x tile to bf16 LDS
  #pragma unroll
  for (int i = 0; i < 16; i++) {
    int c0 = (w + i * 4) * 2;
    ushort e0 = (ushort)f2bf(fmaf(va[i], sm_s[c0],     sm_t[c0]));
    ushort e1 = (ushort)f2bf(fmaf(vb[i], sm_s[c0 + 1], sm_t[c0 + 1]));
    *(uint*)&xn[lane][c0] = ((uint)e1 << 16) | e0;
  }
  __syncthreads();   // xn/WL visible

  int l15 = lane & 15, kh = lane >> 4;
  f4v acc[12];
  #pragma unroll
  for (int nt = 0; nt < 12; nt++) acc[nt] = (f4v){0.f, 0.f, 0.f, 0.f};
  #pragma unroll
  for (int ks = 0; ks < 4; ks++) {
    s8v a = *(s8v*)&xn[w * 16 + l15][ks * 32 + kh * 8];
    #pragma unroll
    for (int nt = 0; nt < 12; nt++) {
      s8v wf = *(s8v*)&WL[nt * 16 + l15][ks * 32 + kh * 8];
      if (nbase + nt * 16 < 256)    // q/k tile: swapped operands
        acc[nt] = __builtin_amdgcn_mfma_f32_16x16x32_bf16(wf, a, acc[nt], 0, 0, 0);
      else                           // v tile
        acc[nt] = __builtin_amdgcn_mfma_f32_16x16x32_bf16(a, wf, acc[nt], 0, 0, 0);
    }
  }
  #pragma unroll
  for (int nt = 0; nt < 12; nt++) {
    if (nbase + nt * 16 < 256) {
      // lane holds o = nbase+nt*16+kh*4+r, px = pbase+w*16+l15
      int ob  = nt * 16 + kh * 4;
      int o0i = nbase + ob;
      int hd  = (o0i & 127) >> 5, d0 = o0i & 31;
      int bh2 = b * 4 + hd;
      int px  = pbase + w * 16 + l15;
      short* dst = (o0i >> 7) ? kb : qb;
      ushort e0 = (ushort)f2bf(acc[nt][0] + bcs[ob + 0]);
      ushort e1 = (ushort)f2bf(acc[nt][1] + bcs[ob + 1]);
      ushort e2 = (ushort)f2bf(acc[nt][2] + bcs[ob + 2]);
      ushort e3 = (ushort)f2bf(acc[nt][3] + bcs[ob + 3]);
      uint2 pk = make_uint2(((uint)e1 << 16) | e0, ((uint)e3 << 16) | e2);
      *(uint2*)&dst[((size_t)bh2 * 4096 + px) * 32 + d0] = pk;
    } else {
      // lane holds o = nbase+nt*16+l15, px = pbase+w*16+kh*4+r
      int o   = nbase + nt * 16 + l15;
      int hd  = (o & 127) >> 5, d = o & 31;
      int bh2 = b * 4 + hd;
      int px0 = pbase + w * 16 + kh * 4;
      float bias = bcs[nt * 16 + l15];
      ushort s0 = (ushort)f2bf(acc[nt][0] + bias);
      ushort s1 = (ushort)f2bf(acc[nt][1] + bias);
      ushort s2 = (ushort)f2bf(acc[nt][2] + bias);
      ushort s3 = (ushort)f2bf(acc[nt][3] + bias);
      uint2 pk2 = make_uint2(((uint)s1 << 16) | s0, ((uint)s3 << 16) | s2);
      *(uint2*)&vtb[((size_t)bh2 * 32 + d) * 4096 + px0] = pk2;
    }
  }
}

// K3: MFMA neighborhood attention + fused out-projection, 2 query rows per block.
// No LDS union: Wo/tile have their own buffers (119 KB total), so Wo staging
// issues at kernel start and overlaps the attention phase; 2 barriers total.
__global__ __launch_bounds__(512) void k3_attn_proj(
    const short* __restrict__ qb, const short* __restrict__ kb, const short* __restrict__ vtb,
    const float* __restrict__ rpb, const short* __restrict__ WoB,
    const float* __restrict__ bo, float* __restrict__ out) {
  __shared__ ushort K_s[8][64][32];      // 32 KB
  __shared__ ushort VT_s[8][32][68];     // 34 KB
  __shared__ ushort P_s[8][16][40];      // 10 KB
  __shared__ ushort Wo_s[128][136];      // 34 KB
  __shared__ ushort tile_s[2][16][136];  // 8.5 KB
  __shared__ float  rpb_s[176];

  int lb    = blockIdx.x;           // 0..255
  int bh    = lb & 7;               // XCD swizzle: each XCD owns one bh
  int chunk = lb >> 3;              // 0..31
  int y0    = chunk * 2;
  int head  = bh & 3, b = bh >> 2;
  int tid   = threadIdx.x;
  int w     = __builtin_amdgcn_readfirstlane(tid >> 6);  // 0..7
  int lane  = tid & 63, l15 = lane & 15, kh = lane >> 4;
  int wsub  = w & 3, rsel = w >> 2;
  int y     = y0 + rsel;
  int ys0   = min(max(y0 - 3, 0), 57);
  int ysoff = min(max(y - 3, 0), 57) - ys0;   // 0 or 1

  // stage K window (8 rows x 64 col x 32 ch bf16)
  {
    const size_t kbase = (size_t)bh * 4096 * 32;
    #pragma unroll
    for (int i = 0; i < 4; i++) {
      int cc = tid + i * 512;
      int row = cc >> 8, rem = cc & 255;
      int col = rem >> 2, ch8 = (rem & 3) * 8;
      int yr = min(ys0 + row, 63);
      *(s8v*)&K_s[row][col][ch8] = *(const s8v*)&kb[kbase + (size_t)(yr * 64 + col) * 32 + ch8];
    }
  }
  // stage VT window (8 rows x 32 d x 64 px bf16)
  {
    const size_t vbase = (size_t)bh * 32 * 4096;
    #pragma unroll
    for (int i = 0; i < 4; i++) {
      int cc = tid + i * 512;
      int row = cc >> 8, rem = cc & 255;
      int d = rem >> 3, c8 = (rem & 7) * 8;
      int yr = min(ys0 + row, 63);
      *(s8v*)&VT_s[row][d][c8] = *(const s8v*)&vtb[vbase + (size_t)d * 4096 + yr * 64 + c8];
    }
  }
  // stage Wo (overlaps attention phase on its own buffer)
  #pragma unroll
  for (int i = 0; i < 4; i++) {
    int cc = tid + i * 512;
    int row = cc >> 4, c8 = (cc & 15) * 8;
    *(s8v*)&Wo_s[row][c8] = *(const s8v*)&WoB[row * 128 + c8];
  }
  if (tid < 169) rpb_s[tid] = rpb[head * 169 + tid];
  __syncthreads();

  int c0  = wsub * 8 + (wsub >> 1) * 8;   // strip col window start: 0,8,24,32
  int xq  = wsub * 16 + l15;              // query x
  int xs  = min(max(xq - 3, 0), 57);
  int pbw = 3 + max(3 - xq, 0) + min(60 - xq, 0);
  int pbh = 3 + max(3 - y, 0) + min(60 - y, 0);

  s8v qf = *(const s8v*)&qb[((size_t)bh * 4096 + y * 64 + xq) * 32 + kh * 8];

  int   bidx[8];
  float badd[8];
  #pragma unroll
  for (int j = 0; j < 8; ++j) {
    int cc = (j >> 2) * 16 + kh * 4 + (j & 3);
    int dx = c0 + cc - xs;
    bool valid = (dx >= 0) && (dx < 7);
    bidx[j] = pbw + min(max(dx, 0), 6);
    badd[j] = valid ? 0.f : -1e30f;
  }

  const f4v zero = {0.f, 0.f, 0.f, 0.f};
  f4v o0 = zero, o1 = zero;
  float ssum = 0.f;

  #pragma unroll
  for (int row = 0; row < 7; ++row) {
    int kr = ysoff + row;
    s8v ka0 = *(s8v*)&K_s[kr][c0 + l15][kh * 8];
    s8v ka1 = *(s8v*)&K_s[kr][c0 + 16 + l15][kh * 8];
    f4v lg0 = __builtin_amdgcn_mfma_f32_16x16x32_bf16(ka0, qf, zero, 0, 0, 0);
    f4v lg1 = __builtin_amdgcn_mfma_f32_16x16x32_bf16(ka1, qf, zero, 0, 0, 0);
    int rbase = (pbh + row) * 13;
    float p[8];
    #pragma unroll
    for (int j = 0; j < 4; ++j) {
      p[j]     = __expf(lg0[j] + rpb_s[rbase + bidx[j]]     + badd[j]);
      p[j + 4] = __expf(lg1[j] + rpb_s[rbase + bidx[j + 4]] + badd[j + 4]);
      ssum += p[j] + p[j + 4];
    }
    uint u0 = ((uint)(ushort)f2bf(p[1]) << 16) | (ushort)f2bf(p[0]);
    uint u1 = ((uint)(ushort)f2bf(p[3]) << 16) | (ushort)f2bf(p[2]);
    uint u2 = ((uint)(ushort)f2bf(p[5]) << 16) | (ushort)f2bf(p[4]);
    uint u3 = ((uint)(ushort)f2bf(p[7]) << 16) | (ushort)f2bf(p[6]);
    *(uint2*)&P_s[w][l15][kh * 4]      = make_uint2(u0, u1);
    *(uint2*)&P_s[w][l15][16 + kh * 4] = make_uint2(u2, u3);
    s8v pa  = *(s8v*)&P_s[w][l15][kh * 8];
    s8v vt0 = *(s8v*)&VT_s[kr][l15][c0 + kh * 8];
    s8v vt1 = *(s8v*)&VT_s[kr][16 + l15][c0 + kh * 8];
    o0 = __builtin_amdgcn_mfma_f32_16x16x32_bf16(pa, vt0, o0, 0, 0, 0);
    o1 = __builtin_amdgcn_mfma_f32_16x16x32_bf16(pa, vt1, o1, 0, 0, 0);
  }

  ssum += __shfl_xor(ssum, 16, 64);
  ssum += __shfl_xor(ssum, 32, 64);

  // write attention tile (own buffer -> no barrier needed before this)
  {
    int col = wsub * 4 + kh;
    #pragma unroll
    for (int r = 0; r < 4; ++r) {
      float sq = __builtin_bit_cast(float,
          __builtin_amdgcn_ds_bpermute((kh * 4 + r) << 2, __builtin_bit_cast(int, ssum)));
      float inv = 1.f / sq;
      tile_s[rsel][col][r * 32 + l15]      = (ushort)f2bf(o0[r] * inv);
      tile_s[rsel][col][r * 32 + 16 + l15] = (ushort)f2bf(o1[r] * inv);
    }
  }
  __syncthreads();

  // out-projection: wave (wsub,rsel) owns outputs o = wsub*32 + nt*16 + l15 for its row
  f4v acc2[2];
  acc2[0] = zero; acc2[1] = zero;
  #pragma unroll
  for (int ks = 0; ks < 4; ks++) {
    s8v a = *(s8v*)&tile_s[rsel][l15][ks * 32 + kh * 8];
    #pragma unroll
    for (int nt = 0; nt < 2; nt++) {
      s8v bf = *(s8v*)&Wo_s[wsub * 32 + nt * 16 + l15][ks * 32 + kh * 8];
      acc2[nt] = __builtin_amdgcn_mfma_f32_16x16x32_bf16(a, bf, acc2[nt], 0, 0, 0);
    }
  }
  int pxg = (head * 16 + (y >> 2)) * 64 + ((y & 3) << 4);
  #pragma unroll
  for (int nt = 0; nt < 2; nt++) {
    int o = wsub * 32 + nt * 16 + l15;
    float bias = bo[o];
    float4 val = make_float4(acc2[nt][0] + bias, acc2[nt][1] + bias,
                             acc2[nt][2] + bias, acc2[nt][3] + bias);
    *(float4*)&out[((size_t)b * 128 + o) * 4096 + pxg + kh * 4] = val;
  }
}

extern "C" void kernel_launch(void* const* d_in, const int* in_sizes, int n_in,
                              void* d_out, int out_size, void* d_ws, size_t ws_size,
                              hipStream_t stream) {
  (void)in_sizes; (void)n_in; (void)out_size; (void)ws_size;
  const float* x   = (const float*)d_in[0];
  const float* gw  = (const float*)d_in[1];
  const float* gb  = (const float*)d_in[2];
  const float* wq  = (const float*)d_in[3];
  const float* bq  = (const float*)d_in[4];
  const float* wk  = (const float*)d_in[5];
  const float* bk  = (const float*)d_in[6];
  const float* wv  = (const float*)d_in[7];
  const float* bv  = (const float*)d_in[8];
  const float* wo  = (const float*)d_in[9];
  const float* bo  = (const float*)d_in[10];
  const float* rpb = (const float*)d_in[11];
  float* ws     = (float*)d_ws;
  float* Spart  = ws + OFF_SP;
  float* S2part = ws + OFF_S2P;
  short* Wcb    = (short*)(ws + OFF_WCB);
  float* bc     = ws + OFF_BC;
  short* qb     = (short*)(ws + OFF_QB);
  short* kb     = (short*)(ws + OFF_KB);
  short* vtb    = (short*)(ws + OFF_VTB);
  short* WoB    = (short*)(ws + OFF_WOB);
  float* out    = (float*)d_out;

  hipLaunchKernelGGL(kP, dim3(320), dim3(256), 0, stream,
                     wq, bq, wk, bk, wv, bv, wo, x, Wcb, bc, WoB, Spart, S2part);
  hipLaunchKernelGGL(k2_qkv, dim3(256), dim3(256), 0, stream,
                     x, Spart, S2part, gw, gb, Wcb, bc, qb, kb, vtb);
  hipLaunchKernelGGL(k3_attn_proj, dim3(256), dim3(512), 0, stream,
                     qb, kb, vtb, rpb, WoB, bo, out);
}